// Round 1
// baseline (826.579 us; speedup 1.0000x reference)
//
#include <hip/hip_runtime.h>
#include <hip/hip_bf16.h>
#include <hip/hip_fp16.h>

// Problem constants
#define B_   2048
#define NN   128    // NMAX
#define MM   64     // HN
#define HD_  128
#define IND  18
#define FD_  16

// K matrix LDS geometry (exp-space Sinkhorn).
// Real size 65 rows x 129 cols; padded with ZEROS (exp-space: zero entries are inert).
#define KR_ROWS 66
#define KR_COLS 136   // 129 -> 136 halves; row = 272 B (16B aligned)
#define KT_ROWS 132   // 129 -> 132
#define KT_COLS 72    // 66 -> 72 halves; row = 144 B (16B aligned)

typedef _Float16 h2_t __attribute__((ext_vector_type(2)));

__device__ __forceinline__ float fdot2f(unsigned int a, unsigned int b, float c) {
#if defined(__has_builtin)
#if __has_builtin(__builtin_amdgcn_fdot2)
  return __builtin_amdgcn_fdot2(__builtin_bit_cast(h2_t, a),
                                __builtin_bit_cast(h2_t, b), c, false);
#else
  h2_t x = __builtin_bit_cast(h2_t, a), y = __builtin_bit_cast(h2_t, b);
  return c + (float)x[0] * (float)y[0] + (float)x[1] * (float)y[1];
#endif
#else
  h2_t x = __builtin_bit_cast(h2_t, a), y = __builtin_bit_cast(h2_t, b);
  return c + (float)x[0] * (float)y[0] + (float)x[1] * (float)y[1];
#endif
}

__device__ __forceinline__ unsigned int pack_h2(float a, float b) {
  __half ha = __float2half_rn(a), hb = __float2half_rn(b);
  return (unsigned int)__half_as_ushort(ha) | ((unsigned int)__half_as_ushort(hb) << 16);
}

__device__ __forceinline__ float bf2f(unsigned short u) {
  union { float f; unsigned int i; } z; z.i = ((unsigned int)u) << 16; return z.f;
}
__device__ __forceinline__ unsigned short f2bf(float f) {
  union { float fv; unsigned int u; } z; z.fv = f;
  unsigned int lsb = (z.u >> 16) & 1u;
  return (unsigned short)((z.u + 0x7fffu + lsb) >> 16);
}

// ---------------------------------------------------------------------------
// Kernel A: per (batch, stream) OT problem. grid (2048, 2), block 256.
// Computes scores -> K = exp(relu(scores)) (f16, dual layout in LDS),
// runs exp-space Sinkhorn (max 100 iters, early exit on convergence),
// writes Pm = K * u * v (bf16) to ws.
// ---------------------------------------------------------------------------
__launch_bounds__(256, 4)
__global__ void ot_kernel(const float* __restrict__ x,
                          const float* __restrict__ w1,
                          const float* __restrict__ w2,
                          const float* __restrict__ fc2w, const float* __restrict__ fc2b,
                          const float* __restrict__ fc3w, const float* __restrict__ fc3b,
                          const float* __restrict__ bin_score,
                          unsigned short* __restrict__ Pbuf)
{
  __shared__ __align__(16) __half Kr[KR_ROWS * KR_COLS];
  __shared__ __align__(16) __half Kt[KT_ROWS * KT_COLS];
  __shared__ __align__(16) float u_s[66];
  __shared__ __align__(16) float v_s[132];
  __shared__ __align__(16) unsigned int uh[36];   // packed f16 u (KT_COLS/2 words)
  __shared__ __align__(16) unsigned int vh[68];   // packed f16 v (KR_COLS/2 words)
  __shared__ int conv_flag;

  const int tid = threadIdx.x;
  const int b = blockIdx.x;
  const int s = blockIdx.y;

  const int n = tid & 127;   // score column (node)
  const int h = tid >> 7;    // which 32-row half of m

  // Phase-1 scratch aliases (dead before Kr/Kt are written; barriers order them)
  float* wstage = reinterpret_cast<float*>(Kr);   // [64][8] w chunk
  float* fcw_s  = reinterpret_cast<float*>(Kt);   // [128][ind] + bias at 2048

  const float* fw = s ? fc3w : fc2w;
  const float* fb = s ? fc3b : fc2b;
  const float* wm = s ? w2 : w1;
  const int ind  = s ? 16 : 2;
  const int xoff = s ? 2 : 0;

  for (int i = tid; i < 128 * ind; i += 256) fcw_s[i] = fw[i];
  if (tid < 128) fcw_s[2048 + tid] = fb[tid];

  float xr[16];
  {
    const float* xp = x + ((size_t)b * NN + n) * IND + xoff;
    for (int i = 0; i < 16; ++i) xr[i] = (i < ind) ? xp[i] : 0.0f;
  }
  __syncthreads();

  // ---- Phase 1: scores[m][n] = relu(sum_c act[n][c] * wm[m][c]) ----
  float acc[32];
  #pragma unroll
  for (int i = 0; i < 32; ++i) acc[i] = 0.0f;

  for (int ch = 0; ch < 16; ++ch) {
    const int c0 = ch * 8;
    __syncthreads();
    {
      int i0 = tid * 2;
      wstage[i0]     = wm[(i0 >> 3) * 128 + c0 + (i0 & 7)];
      wstage[i0 + 1] = wm[((i0 + 1) >> 3) * 128 + c0 + ((i0 + 1) & 7)];
    }
    __syncthreads();
    float act[8];
    #pragma unroll
    for (int c = 0; c < 8; ++c) {
      const int cc = c0 + c;
      float sa = fcw_s[2048 + cc];
      for (int i = 0; i < ind; ++i) sa += xr[i] * fcw_s[cc * ind + i];
      act[c] = fmaxf(sa, 0.0f);
    }
    const float4* wst4 = reinterpret_cast<const float4*>(wstage);
    #pragma unroll
    for (int mi = 0; mi < 32; ++mi) {
      const int m = (h << 5) + mi;
      float4 wa = wst4[m * 2];
      float4 wb = wst4[m * 2 + 1];
      acc[mi] += act[0]*wa.x + act[1]*wa.y + act[2]*wa.z + act[3]*wa.w
               + act[4]*wb.x + act[5]*wb.y + act[6]*wb.z + act[7]*wb.w;
    }
  }
  __syncthreads();  // scratch (wstage/fcw_s) dead; safe to write Kr/Kt

  const float ebs = __expf(bin_score[0]);
  const __half ebs_h = __float2half_rn(ebs);
  const __half zero_h = __ushort_as_half((unsigned short)0);

  // edges + zero padding
  for (int idx = tid; idx < KR_ROWS * KR_COLS; idx += 256) {
    const int m = idx / KR_COLS, c = idx - m * KR_COLS;
    if (m < 64 && c < 128) continue;
    Kr[idx] = (m <= 64 && c <= 128) ? ebs_h : zero_h;
  }
  for (int idx = tid; idx < KT_ROWS * KT_COLS; idx += 256) {
    const int c = idx / KT_COLS, m = idx - c * KT_COLS;
    if (c < 128 && m < 64) continue;
    Kt[idx] = (c <= 128 && m <= 64) ? ebs_h : zero_h;
  }
  // main block K = exp(relu(scores)), clamped for f16 safety
  #pragma unroll
  for (int mi = 0; mi < 32; ++mi) {
    const int m = (h << 5) + mi;
    float k = fminf(__expf(fmaxf(acc[mi], 0.0f)), 60000.0f);
    __half kh = __float2half_rn(k);
    Kr[m * KR_COLS + n] = kh;
    Kt[n * KT_COLS + m] = kh;
  }
  // u, v init (v0 = exp(0) = 1 on real cols)
  if (tid < 66) u_s[tid] = 0.0f;
  if (tid < 132) v_s[tid] = (tid < 129) ? 1.0f : 0.0f;
  if (tid < 68) {
    unsigned int oneh = (unsigned int)__half_as_ushort(__float2half_rn(1.0f));
    unsigned int w;
    if (tid < 64) w = oneh | (oneh << 16);
    else if (tid == 64) w = oneh;   // (v[128]=1, v[129]=0)
    else w = 0u;
    vh[tid] = w;
  }
  if (tid < 36) uh[tid] = 0u;
  __syncthreads();

  // ---- Phase 2: exp-space Sinkhorn. mu* = {1,...,1,128}, nu* = {1,...,1,64} ----
  for (int it = 0; it < 100; ++it) {
    if (tid == 0) conv_flag = 0;
    __syncthreads();
    if (tid < 65) {  // row pass: u = mu* / (K v)
      const uint4* kr4 = reinterpret_cast<const uint4*>(Kr + tid * KR_COLS);
      const uint4* vh4 = reinterpret_cast<const uint4*>(vh);
      float a0 = 0.f, a1 = 0.f, a2 = 0.f, a3 = 0.f;
      #pragma unroll
      for (int j = 0; j < 17; ++j) {
        uint4 kk = kr4[j]; uint4 vv = vh4[j];
        a0 = fdot2f(kk.x, vv.x, a0);
        a1 = fdot2f(kk.y, vv.y, a1);
        a2 = fdot2f(kk.z, vv.z, a2);
        a3 = fdot2f(kk.w, vv.w, a3);
      }
      float ssum = (a0 + a1) + (a2 + a3);
      float un = ((tid == 64) ? 128.0f : 1.0f) / ssum;
      float uo = u_s[tid];
      if (fabsf(un - uo) > 1e-5f * un) conv_flag = 1;
      u_s[tid] = un;
      float up = __shfl_xor(un, 1);
      if (tid == 64) up = 0.0f;     // row 65 is zero
      if (!(tid & 1)) uh[tid >> 1] = pack_h2(un, up);
    }
    __syncthreads();
    if (tid < 129) {  // col pass: v = nu* / (K^T u)
      const uint4* kt4 = reinterpret_cast<const uint4*>(Kt + tid * KT_COLS);
      const uint4* uh4 = reinterpret_cast<const uint4*>(uh);
      float a0 = 0.f, a1 = 0.f, a2 = 0.f, a3 = 0.f;
      #pragma unroll
      for (int j = 0; j < 9; ++j) {
        uint4 kk = kt4[j]; uint4 uu = uh4[j];
        a0 = fdot2f(kk.x, uu.x, a0);
        a1 = fdot2f(kk.y, uu.y, a1);
        a2 = fdot2f(kk.z, uu.z, a2);
        a3 = fdot2f(kk.w, uu.w, a3);
      }
      float ssum = (a0 + a1) + (a2 + a3);
      float vn = ((tid == 128) ? 64.0f : 1.0f) / ssum;
      float vo = v_s[tid];
      if (fabsf(vn - vo) > 1e-5f * vn) conv_flag = 1;
      v_s[tid] = vn;
      float vp = __shfl_xor(vn, 1);
      if (tid == 128) vp = 0.0f;    // col 129 is zero
      if (!(tid & 1)) vh[tid >> 1] = pack_h2(vn, vp);
    }
    __syncthreads();
    int done = (conv_flag == 0);
    __syncthreads();   // everyone reads flag before next reset
    if (done) break;
  }

  // ---- Phase 3: Pm[m][n] = K * u * v (scale folded into mu*/nu*) ----
  {
    unsigned short* Pout = Pbuf + ((size_t)(s * B_ + b)) * (MM * NN);
    for (int idx = tid; idx < MM * NN; idx += 256) {
      int m = idx >> 7, c = idx & 127;
      float p = __half2float(Kr[m * KR_COLS + c]) * u_s[m] * v_s[c];
      Pout[idx] = f2bf(p);
    }
  }
}

// ---------------------------------------------------------------------------
// Kernel B: per batch. Pc = a*Ps + (1-a)*Pf; adj_al = Pc@adj; al2 = adj_al@Pc^T;
// LN1 -> lnadj (bf16). feats_al = Pc@xf; LN2 -> lnfeats (bf16). grid 2048.
// ---------------------------------------------------------------------------
#define PC_S 132
__launch_bounds__(256, 2)
__global__ void align_kernel(const unsigned short* __restrict__ Pbuf,
                             const float* __restrict__ adj,
                             const float* __restrict__ x,
                             const float* __restrict__ alpha_p,
                             const float* __restrict__ ln1g, const float* __restrict__ ln1b,
                             const float* __restrict__ ln2g, const float* __restrict__ ln2b,
                             unsigned short* __restrict__ lnadj,
                             unsigned short* __restrict__ lnfeats)
{
  __shared__ __align__(16) float Pc[64 * PC_S];
  __shared__ __align__(16) unsigned short AAl[64 * PC_S];
  __shared__ __align__(16) float chunk[16 * 128];   // adj chunk / xf
  __shared__ float red[16];
  __shared__ float stats[2];

  const int tid = threadIdx.x;
  const int b = blockIdx.x;
  const float a = 1.0f / (1.0f + __expf(-alpha_p[0]));

  const unsigned short* Ps = Pbuf + (size_t)b * (64 * 128);
  const unsigned short* Pf = Pbuf + ((size_t)B_ + b) * (64 * 128);
  for (int idx = tid; idx < 64 * 128; idx += 256) {
    int m = idx >> 7, c = idx & 127;
    Pc[m * PC_S + c] = a * bf2f(Ps[idx]) + (1.0f - a) * bf2f(Pf[idx]);
  }
  __syncthreads();

  // adj_al = Pc @ adj[b]  (64x128)
  {
    const int dg = (tid & 31) * 4;
    const int m0 = (tid >> 5) * 8;
    float ac[8][4];
    #pragma unroll
    for (int i = 0; i < 8; ++i)
      #pragma unroll
      for (int j = 0; j < 4; ++j) ac[i][j] = 0.0f;
    for (int n0 = 0; n0 < 128; n0 += 16) {
      __syncthreads();
      for (int i = tid; i < 16 * 128; i += 256) {
        int nn = i >> 7, d = i & 127;
        chunk[i] = adj[((size_t)b * NN + (n0 + nn)) * NN + d];
      }
      __syncthreads();
      #pragma unroll
      for (int nn = 0; nn < 16; ++nn) {
        const float4 av = *reinterpret_cast<const float4*>(&chunk[nn * 128 + dg]);
        #pragma unroll
        for (int mi = 0; mi < 8; ++mi) {
          float p = Pc[(m0 + mi) * PC_S + n0 + nn];
          ac[mi][0] += p * av.x; ac[mi][1] += p * av.y;
          ac[mi][2] += p * av.z; ac[mi][3] += p * av.w;
        }
      }
    }
    __syncthreads();
    #pragma unroll
    for (int mi = 0; mi < 8; ++mi) {
      ushort4 st;
      st.x = f2bf(ac[mi][0]); st.y = f2bf(ac[mi][1]);
      st.z = f2bf(ac[mi][2]); st.w = f2bf(ac[mi][3]);
      *reinterpret_cast<ushort4*>(&AAl[(m0 + mi) * PC_S + dg]) = st;
    }
  }
  __syncthreads();

  // al2[m][k] = sum_d adj_al[m][d] * Pc[k][d]; then LN1 over 4096
  {
    const int m0 = (tid >> 4) * 4;
    const int k0 = (tid & 15) * 4;
    float c2[4][4];
    #pragma unroll
    for (int i = 0; i < 4; ++i)
      #pragma unroll
      for (int j = 0; j < 4; ++j) c2[i][j] = 0.0f;
    for (int d = 0; d < 128; d += 4) {
      float4 pv[4];
      #pragma unroll
      for (int ki = 0; ki < 4; ++ki)
        pv[ki] = *reinterpret_cast<const float4*>(&Pc[(k0 + ki) * PC_S + d]);
      #pragma unroll
      for (int mi = 0; mi < 4; ++mi) {
        ushort4 us = *reinterpret_cast<const ushort4*>(&AAl[(m0 + mi) * PC_S + d]);
        float a0 = bf2f(us.x), a1 = bf2f(us.y), a2 = bf2f(us.z), a3 = bf2f(us.w);
        #pragma unroll
        for (int ki = 0; ki < 4; ++ki)
          c2[mi][ki] += a0 * pv[ki].x + a1 * pv[ki].y + a2 * pv[ki].z + a3 * pv[ki].w;
      }
    }
    float lsum = 0.f, lsq = 0.f;
    #pragma unroll
    for (int mi = 0; mi < 4; ++mi)
      #pragma unroll
      for (int ki = 0; ki < 4; ++ki) { lsum += c2[mi][ki]; lsq += c2[mi][ki] * c2[mi][ki]; }
    for (int off = 32; off; off >>= 1) { lsum += __shfl_down(lsum, off); lsq += __shfl_down(lsq, off); }
    int wv = tid >> 6;
    if ((tid & 63) == 0) { red[wv] = lsum; red[8 + wv] = lsq; }
    __syncthreads();
    if (tid == 0) {
      float s0 = red[0] + red[1] + red[2] + red[3];
      float s1 = red[8] + red[9] + red[10] + red[11];
      float mean = s0 / 4096.0f;
      float var = s1 / 4096.0f - mean * mean;
      stats[0] = mean; stats[1] = rsqrtf(var + 1e-5f);
    }
    __syncthreads();
    float mean = stats[0], rstd = stats[1];
    #pragma unroll
    for (int mi = 0; mi < 4; ++mi)
      #pragma unroll
      for (int ki = 0; ki < 4; ++ki) {
        int pos = (m0 + mi) * 64 + (k0 + ki);
        float vv = (c2[mi][ki] - mean) * rstd * ln1g[pos] + ln1b[pos];
        lnadj[(size_t)b * 4096 + pos] = f2bf(vv);
      }
  }
  __syncthreads();

  // feats_al = Pc @ xf (64x16); LN2 over 1024
  for (int i = tid; i < 128 * 16; i += 256) {
    int nn = i >> 4, f = i & 15;
    chunk[i] = x[((size_t)b * NN + nn) * IND + 2 + f];
  }
  __syncthreads();
  {
    const int m = tid >> 2;
    const int f0 = (tid & 3) * 4;
    float c3[4] = {0.f, 0.f, 0.f, 0.f};
    for (int nn = 0; nn < 128; ++nn) {
      float p = Pc[m * PC_S + nn];
      const float4 xv = *reinterpret_cast<const float4*>(&chunk[nn * 16 + f0]);
      c3[0] += p * xv.x; c3[1] += p * xv.y; c3[2] += p * xv.z; c3[3] += p * xv.w;
    }
    float lsum = c3[0] + c3[1] + c3[2] + c3[3];
    float lsq = c3[0]*c3[0] + c3[1]*c3[1] + c3[2]*c3[2] + c3[3]*c3[3];
    for (int off = 32; off; off >>= 1) { lsum += __shfl_down(lsum, off); lsq += __shfl_down(lsq, off); }
    int wv = tid >> 6;
    if ((tid & 63) == 0) { red[wv] = lsum; red[8 + wv] = lsq; }
    __syncthreads();
    if (tid == 0) {
      float s0 = red[0] + red[1] + red[2] + red[3];
      float s1 = red[8] + red[9] + red[10] + red[11];
      float mean = s0 / 1024.0f;
      float var = s1 / 1024.0f - mean * mean;
      stats[0] = mean; stats[1] = rsqrtf(var + 1e-5f);
    }
    __syncthreads();
    float mean = stats[0], rstd = stats[1];
    #pragma unroll
    for (int j = 0; j < 4; ++j) {
      int pos = m * 16 + f0 + j;
      float vv = (c3[j] - mean) * rstd * ln2g[pos] + ln2b[pos];
      lnfeats[(size_t)b * 1024 + pos] = f2bf(vv);
    }
  }
}

// ---------------------------------------------------------------------------
// Kernel C: C[M][ldc] (+coff) = relu(A_bf16[M][K] @ W[N][K]^T + bias). Tiles 64x32.
// ---------------------------------------------------------------------------
__launch_bounds__(256)
__global__ void gemm_bf16_kernel(const unsigned short* __restrict__ A,
                                 const float* __restrict__ W,
                                 const float* __restrict__ bias,
                                 float* __restrict__ C,
                                 int M, int N, int K, int ldc, int coff)
{
  __shared__ __align__(16) float At[16][68];
  __shared__ __align__(16) float Wt[16][36];
  const int tid = threadIdx.x;
  const int m0g = blockIdx.x * 64;
  const int n0g = blockIdx.y * 32;
  const int mi0 = (tid >> 4) * 4;
  const int ni0 = (tid & 15) * 2;
  float acc[4][2];
  #pragma unroll
  for (int i = 0; i < 4; ++i) { acc[i][0] = 0.f; acc[i][1] = 0.f; }

  for (int kc = 0; kc < K; kc += 16) {
    __syncthreads();
    {
      int r = tid >> 2, ko = (tid & 3) * 4;
      const ushort4 us = *reinterpret_cast<const ushort4*>(&A[(size_t)(m0g + r) * K + kc + ko]);
      At[ko + 0][r] = bf2f(us.x); At[ko + 1][r] = bf2f(us.y);
      At[ko + 2][r] = bf2f(us.z); At[ko + 3][r] = bf2f(us.w);
    }
    {
      int r = tid >> 3, ko = (tid & 7) * 2;
      const float2 wv = *reinterpret_cast<const float2*>(&W[(size_t)(n0g + r) * K + kc + ko]);
      Wt[ko][r] = wv.x; Wt[ko + 1][r] = wv.y;
    }
    __syncthreads();
    #pragma unroll
    for (int kk = 0; kk < 16; ++kk) {
      const float4 av = *reinterpret_cast<const float4*>(&At[kk][mi0]);
      const float2 wv = *reinterpret_cast<const float2*>(&Wt[kk][ni0]);
      acc[0][0] += av.x * wv.x; acc[0][1] += av.x * wv.y;
      acc[1][0] += av.y * wv.x; acc[1][1] += av.y * wv.y;
      acc[2][0] += av.z * wv.x; acc[2][1] += av.z * wv.y;
      acc[3][0] += av.w * wv.x; acc[3][1] += av.w * wv.y;
    }
  }
  #pragma unroll
  for (int j = 0; j < 2; ++j) {
    float bb = bias[n0g + ni0 + j];
    #pragma unroll
    for (int i = 0; i < 4; ++i) {
      float vv = fmaxf(acc[i][j] + bb, 0.0f);
      C[(size_t)(m0g + mi0 + i) * ldc + coff + n0g + ni0 + j] = vv;
    }
  }
}

// ---------------------------------------------------------------------------
// Kernel D: per 4 rows: fc6(relu) -> fc7 -> log_softmax. grid 512, block 256.
// ---------------------------------------------------------------------------
__launch_bounds__(256)
__global__ void head_kernel(const float* __restrict__ h45,
                            const float* __restrict__ wT6,   // [512][64]
                            const float* __restrict__ b6,
                            const float* __restrict__ w7,    // [10][64]
                            const float* __restrict__ b7,
                            float* __restrict__ out)
{
  __shared__ float row[4][512];
  __shared__ float h6[4][64];
  const int tid = threadIdx.x;
  const int r0 = blockIdx.x * 4;
  for (int i = tid; i < 4 * 512; i += 256)
    row[i >> 9][i & 511] = h45[(size_t)(r0 + (i >> 9)) * 512 + (i & 511)];
  __syncthreads();
  const int r = tid >> 6, o = tid & 63;
  float accv = b6[o];
  #pragma unroll 8
  for (int k = 0; k < 512; ++k) accv += row[r][k] * wT6[k * 64 + o];
  h6[r][o] = fmaxf(accv, 0.0f);
  __syncthreads();
  float z = -1e30f;
  if (o < 10) {
    float a2 = b7[o];
    #pragma unroll
    for (int k = 0; k < 64; ++k) a2 += h6[r][k] * w7[o * 64 + k];
    z = a2;
  }
  float zs[10];
  #pragma unroll
  for (int j = 0; j < 10; ++j) zs[j] = __shfl(z, j, 64);
  float mx = zs[0];
  #pragma unroll
  for (int j = 1; j < 10; ++j) mx = fmaxf(mx, zs[j]);
  float se = 0.f;
  #pragma unroll
  for (int j = 0; j < 10; ++j) se += __expf(zs[j] - mx);
  if (o < 10) out[(size_t)(r0 + r) * 10 + o] = z - mx - __logf(se);
}

__global__ void transpose_kernel(const float* __restrict__ in, float* __restrict__ outp,
                                 int R, int Cc)
{
  int idx = blockIdx.x * blockDim.x + threadIdx.x;
  int total = R * Cc;
  for (; idx < total; idx += gridDim.x * blockDim.x) {
    int rr = idx / Cc, cc = idx - rr * Cc;
    outp[cc * R + rr] = in[idx];
  }
}

// ---------------------------------------------------------------------------
extern "C" void kernel_launch(void* const* d_in, const int* in_sizes, int n_in,
                              void* d_out, int out_size, void* d_ws, size_t ws_size,
                              hipStream_t stream)
{
  (void)in_sizes; (void)n_in; (void)out_size; (void)ws_size;
  const float* x    = (const float*)d_in[0];
  const float* adj  = (const float*)d_in[1];
  const float* w1   = (const float*)d_in[2];
  const float* w2   = (const float*)d_in[3];
  const float* alpha = (const float*)d_in[4];
  const float* bin_score = (const float*)d_in[5];
  const float* fc2w = (const float*)d_in[6];
  const float* fc2b = (const float*)d_in[7];
  const float* fc3w = (const float*)d_in[8];
  const float* fc3b = (const float*)d_in[9];
  const float* ln1g = (const float*)d_in[10];
  const float* ln1b = (const float*)d_in[11];
  const float* fc4w = (const float*)d_in[12];
  const float* fc4b = (const float*)d_in[13];
  const float* ln2g = (const float*)d_in[14];
  const float* ln2b = (const float*)d_in[15];
  const float* fc5w = (const float*)d_in[16];
  const float* fc5b = (const float*)d_in[17];
  const float* fc6w = (const float*)d_in[18];
  const float* fc6b = (const float*)d_in[19];
  const float* fc7w = (const float*)d_in[20];
  const float* fc7b = (const float*)d_in[21];
  float* out = (float*)d_out;

  char* ws = (char*)d_ws;
  unsigned short* Pbuf = (unsigned short*)ws;                       // 4096*8192 bf16 = 64 MB
  size_t off = (size_t)4096 * 8192 * 2;
  unsigned short* lnadj = (unsigned short*)(ws + off);  off += (size_t)2048 * 4096 * 2;
  unsigned short* lnfeats = (unsigned short*)(ws + off); off += (size_t)2048 * 1024 * 2;
  float* h45 = (float*)(ws + off);                      off += (size_t)2048 * 512 * 4;
  float* wT6 = (float*)(ws + off);                      off += (size_t)512 * 64 * 4;

  hipLaunchKernelGGL(ot_kernel, dim3(2048, 2), dim3(256), 0, stream,
                     x, w1, w2, fc2w, fc2b, fc3w, fc3b, bin_score, Pbuf);
  hipLaunchKernelGGL(transpose_kernel, dim3(32), dim3(256), 0, stream, fc6w, wT6, 64, 512);
  hipLaunchKernelGGL(align_kernel, dim3(2048), dim3(256), 0, stream,
                     Pbuf, adj, x, alpha, ln1g, ln1b, ln2g, ln2b, lnadj, lnfeats);
  hipLaunchKernelGGL(gemm_bf16_kernel, dim3(32, 8), dim3(256), 0, stream,
                     lnadj, fc4w, fc4b, h45, 2048, 256, 4096, 512, 0);
  hipLaunchKernelGGL(gemm_bf16_kernel, dim3(32, 8), dim3(256), 0, stream,
                     lnfeats, fc5w, fc5b, h45, 2048, 256, 1024, 512, 256);
  hipLaunchKernelGGL(head_kernel, dim3(512), dim3(256), 0, stream,
                     h45, wT6, fc6b, fc7w, fc7b, out);
}

// Round 3
// 538.838 us; speedup vs baseline: 1.5340x; 1.5340x over previous
//
#include <hip/hip_runtime.h>
#include <hip/hip_bf16.h>
#include <hip/hip_fp16.h>

// Problem constants
#define B_   2048
#define NN   128    // NMAX
#define MM   64     // HN
#define HD_  128
#define IND  18
#define FD_  16

typedef unsigned int u32;
typedef _Float16 h2_t __attribute__((ext_vector_type(2)));

__device__ __forceinline__ float fdot2f(u32 a, u32 b, float c) {
#if defined(__has_builtin)
#if __has_builtin(__builtin_amdgcn_fdot2)
  return __builtin_amdgcn_fdot2(__builtin_bit_cast(h2_t, a),
                                __builtin_bit_cast(h2_t, b), c, false);
#else
  h2_t x = __builtin_bit_cast(h2_t, a), y = __builtin_bit_cast(h2_t, b);
  return c + (float)x[0] * (float)y[0] + (float)x[1] * (float)y[1];
#endif
#else
  h2_t x = __builtin_bit_cast(h2_t, a), y = __builtin_bit_cast(h2_t, b);
  return c + (float)x[0] * (float)y[0] + (float)x[1] * (float)y[1];
#endif
}

__device__ __forceinline__ u32 pk2(float a, float b) {
#if defined(__has_builtin)
#if __has_builtin(__builtin_amdgcn_cvt_pkrtz)
  return __builtin_bit_cast(u32, __builtin_amdgcn_cvt_pkrtz(a, b));
#else
  __half ha = __float2half_rn(a), hb = __float2half_rn(b);
  return (u32)__half_as_ushort(ha) | ((u32)__half_as_ushort(hb) << 16);
#endif
#else
  __half ha = __float2half_rn(a), hb = __float2half_rn(b);
  return (u32)__half_as_ushort(ha) | ((u32)__half_as_ushort(hb) << 16);
#endif
}

__device__ __forceinline__ float rcpf_(float x) {
#if defined(__has_builtin)
#if __has_builtin(__builtin_amdgcn_rcpf)
  return __builtin_amdgcn_rcpf(x);
#else
  return 1.0f / x;
#endif
#else
  return 1.0f / x;
#endif
}

__device__ __forceinline__ float h_lo(u32 d) {
  return __half2float(__ushort_as_half((unsigned short)(d & 0xffffu)));
}
__device__ __forceinline__ float h_hi(u32 d) {
  return __half2float(__ushort_as_half((unsigned short)(d >> 16)));
}

__device__ __forceinline__ float bf2f(unsigned short u) {
  union { float f; u32 i; } z; z.i = ((u32)u) << 16; return z.f;
}
__device__ __forceinline__ unsigned short f2bf(float f) {
  union { float fv; u32 u; } z; z.fv = f;
  u32 lsb = (z.u >> 16) & 1u;
  return (unsigned short)((z.u + 0x7fffu + lsb) >> 16);
}

// ---------------------------------------------------------------------------
// Kernel A: ONE WAVE per (batch, stream) OT problem. grid (2048,2), block 64.
// No barriers anywhere (single-wave blocks). K register-resident:
//   kr[64]  : lane l holds K row l as packed-f16 col pairs (2j,2j+1)
//   kta/ktb : lane l holds K cols 2l / 2l+1 as packed-f16 row pairs (2j,2j+1)
// Exp-space Sinkhorn: u = mu*/(K v), v = nu*/(K^T u), mu*={1..1,128},
// nu*={1..1,64}; bin row/col analytic via sums. P = K*u*v (verified identity).
// ---------------------------------------------------------------------------
__launch_bounds__(64, 2)
__global__ void ot_kernel(const float* __restrict__ x,
                          const float* __restrict__ w1,
                          const float* __restrict__ w2,
                          const float* __restrict__ fc2w, const float* __restrict__ fc2b,
                          const float* __restrict__ fc3w, const float* __restrict__ fc3b,
                          const float* __restrict__ bin_score,
                          unsigned short* __restrict__ Pbuf)
{
  __shared__ __align__(16) u32 Ksh[64 * 68];      // 64 rows, pitch 68 dwords (136 f16)
  __shared__ __align__(16) u32 acteb[2][64];      // even-node act row (double buffer)
  __shared__ __align__(16) u32 actob[2][64];      // odd-node act row
  __shared__ __align__(16) u32 vhs[64];           // v[0..127] packed f16 pairs
  __shared__ __align__(16) u32 uhs[32];           // u[0..63] packed f16 pairs

  const int l = threadIdx.x;
  const int b = blockIdx.x, s = blockIdx.y;
  const float* wm = s ? w2 : w1;
  const float* fw = s ? fc3w : fc2w;
  const float* fb = s ? fc3b : fc2b;
  const int xoff = s ? 2 : 0;

  // ---- per-lane parameter registers ----
  // fcw rows c=2l, 2l+1 as i-pair f16 dwords, zero-padded to 16 ins
  u32 fcwh[16];
  float bia0 = fb[2 * l], bia1 = fb[2 * l + 1];
  if (s) {
    const float* fr0 = fw + (size_t)(2 * l) * 16;
    const float* fr1 = fr0 + 16;
    #pragma unroll
    for (int j = 0; j < 8; ++j) {
      float2 a = *reinterpret_cast<const float2*>(fr0 + 2 * j);
      float2 c = *reinterpret_cast<const float2*>(fr1 + 2 * j);
      fcwh[j] = pk2(a.x, a.y);
      fcwh[8 + j] = pk2(c.x, c.y);
    }
  } else {
    #pragma unroll
    for (int j = 0; j < 16; ++j) fcwh[j] = 0u;
    fcwh[0] = pk2(fw[(2 * l) * 2], fw[(2 * l) * 2 + 1]);
    fcwh[8] = pk2(fw[(2 * l + 1) * 2], fw[(2 * l + 1) * 2 + 1]);
  }
  // x rows 2l, 2l+1 (this batch), i-pair f16 dwords zero-padded
  u32 xh[16];
  {
    const float* xr0 = x + ((size_t)b * NN + 2 * l) * IND + xoff;
    const float* xr1 = xr0 + IND;
    if (s) {
      #pragma unroll
      for (int j = 0; j < 8; ++j) {
        float2 a = *reinterpret_cast<const float2*>(xr0 + 2 * j);
        float2 c = *reinterpret_cast<const float2*>(xr1 + 2 * j);
        xh[j] = pk2(a.x, a.y);
        xh[8 + j] = pk2(c.x, c.y);
      }
    } else {
      #pragma unroll
      for (int j = 0; j < 16; ++j) xh[j] = 0u;
      xh[0] = pk2(xr0[0], xr0[1]);
      xh[8] = pk2(xr1[0], xr1[1]);
    }
  }
  // w row l (for scores), packed f16 col pairs
  u32 wreg[64];
  {
    const float* wr = wm + (size_t)l * 128;
    #pragma unroll
    for (int k = 0; k < 32; ++k) {
      float4 wv = *reinterpret_cast<const float4*>(wr + 4 * k);
      wreg[2 * k] = pk2(wv.x, wv.y);
      wreg[2 * k + 1] = pk2(wv.z, wv.w);
    }
  }
  const float ebs = __expf(bin_score[0]);

  // ---- Phase 1: K[l][n] = min(exp(relu(score)), 6e4) as f16 into Ksh ----
#define ACT_PAIR(NP, PB) do {                                                 \
    float ae0 = bia0, ae1 = bia1, ao0 = bia0, ao1 = bia1;                     \
    _Pragma("unroll")                                                         \
    for (int j = 0; j < 8; ++j) {                                             \
      u32 xe = __shfl(xh[j], (NP));                                           \
      u32 xo = __shfl(xh[8 + j], (NP));                                       \
      ae0 = fdot2f(fcwh[j], xe, ae0);                                         \
      ae1 = fdot2f(fcwh[8 + j], xe, ae1);                                     \
      ao0 = fdot2f(fcwh[j], xo, ao0);                                         \
      ao1 = fdot2f(fcwh[8 + j], xo, ao1);                                     \
    }                                                                         \
    acteb[(PB)][l] = pk2(fmaxf(ae0, 0.f), fmaxf(ae1, 0.f));                   \
    actob[(PB)][l] = pk2(fmaxf(ao0, 0.f), fmaxf(ao1, 0.f));                   \
  } while (0)

  ACT_PAIR(0, 0);
  for (int np = 0; np < 64; ++np) {
    const int pb = np & 1;
    if (np < 63) { ACT_PAIR(np + 1, (np + 1) & 1); }
    const uint4* ae4 = reinterpret_cast<const uint4*>(acteb[pb]);
    const uint4* ao4 = reinterpret_cast<const uint4*>(actob[pb]);
    float se0 = 0, se1 = 0, se2 = 0, se3 = 0;
    float so0 = 0, so1 = 0, so2 = 0, so3 = 0;
    #pragma unroll
    for (int t = 0; t < 16; ++t) {
      uint4 av = ae4[t];
      uint4 bv = ao4[t];
      se0 = fdot2f(wreg[4 * t + 0], av.x, se0);
      se1 = fdot2f(wreg[4 * t + 1], av.y, se1);
      se2 = fdot2f(wreg[4 * t + 2], av.z, se2);
      se3 = fdot2f(wreg[4 * t + 3], av.w, se3);
      so0 = fdot2f(wreg[4 * t + 0], bv.x, so0);
      so1 = fdot2f(wreg[4 * t + 1], bv.y, so1);
      so2 = fdot2f(wreg[4 * t + 2], bv.z, so2);
      so3 = fdot2f(wreg[4 * t + 3], bv.w, so3);
    }
    float ke = fminf(__expf(fmaxf((se0 + se1) + (se2 + se3), 0.f)), 60000.f);
    float ko = fminf(__expf(fmaxf((so0 + so1) + (so2 + so3), 0.f)), 60000.f);
    Ksh[l * 68 + np] = pk2(ke, ko);
  }
#undef ACT_PAIR

  // ---- Phase 1.5: register tiles ----
  u32 kr[64];
  #pragma unroll
  for (int t = 0; t < 16; ++t) {
    uint4 kv = *reinterpret_cast<const uint4*>(Ksh + l * 68 + 4 * t);
    kr[4 * t + 0] = kv.x; kr[4 * t + 1] = kv.y;
    kr[4 * t + 2] = kv.z; kr[4 * t + 3] = kv.w;
  }
  u32 kta[32], ktb[32];
  #pragma unroll
  for (int j = 0; j < 32; ++j) {
    u32 d0 = Ksh[(2 * j) * 68 + l];
    u32 d1 = Ksh[(2 * j + 1) * 68 + l];
    kta[j] = (d0 & 0xffffu) | (d1 << 16);          // col 2l, rows (2j,2j+1)
    ktb[j] = (d0 >> 16) | (d1 & 0xffff0000u);      // col 2l+1
  }

  // ---- Phase 2: barrier-free exp-space Sinkhorn ----
  vhs[l] = 0x3C003C00u;     // v = 1
  float v128 = 1.0f, sum_v = 129.0f;
  float u_old = 0.0f, vo0 = 1.0f, vo1 = 1.0f;
  float ur = 0.0f;
  const float TOL = 1e-4f;

  for (int it = 0; it < 100; ++it) {
    const float u64v = 128.0f * rcpf_(ebs * sum_v);
    // u-pass: row l
    float a0 = ebs * v128, a1 = 0.f, a2 = 0.f, a3 = 0.f;
    const uint4* vh4 = reinterpret_cast<const uint4*>(vhs);
    #pragma unroll
    for (int t = 0; t < 16; ++t) {
      uint4 vv = vh4[t];
      a0 = fdot2f(kr[4 * t + 0], vv.x, a0);
      a1 = fdot2f(kr[4 * t + 1], vv.y, a1);
      a2 = fdot2f(kr[4 * t + 2], vv.z, a2);
      a3 = fdot2f(kr[4 * t + 3], vv.w, a3);
    }
    float urn = rcpf_((a0 + a1) + (a2 + a3));
    float m1 = fabsf(urn - u_old) - TOL * urn;
    u_old = urn; ur = urn;
    // sum_u butterfly
    float su = urn;
    su += __shfl_xor(su, 1);  su += __shfl_xor(su, 2);
    su += __shfl_xor(su, 4);  su += __shfl_xor(su, 8);
    su += __shfl_xor(su, 16); su += __shfl_xor(su, 32);
    const float sum_u = su + u64v;
    const float v128n = 64.0f * rcpf_(ebs * sum_u);
    // publish u (packed pairs)
    float upr = __shfl_xor(urn, 1);
    if (!(l & 1)) uhs[l >> 1] = pk2(urn, upr);
    // v-pass: cols 2l, 2l+1
    float c0a = ebs * u64v, c0b = 0.f, c1a = ebs * u64v, c1b = 0.f;
    const uint4* uh4 = reinterpret_cast<const uint4*>(uhs);
    #pragma unroll
    for (int t = 0; t < 8; ++t) {
      uint4 uu = uh4[t];
      c0a = fdot2f(kta[4 * t + 0], uu.x, c0a);
      c0b = fdot2f(kta[4 * t + 1], uu.y, c0b);
      c0a = fdot2f(kta[4 * t + 2], uu.z, c0a);
      c0b = fdot2f(kta[4 * t + 3], uu.w, c0b);
      c1a = fdot2f(ktb[4 * t + 0], uu.x, c1a);
      c1b = fdot2f(ktb[4 * t + 1], uu.y, c1b);
      c1a = fdot2f(ktb[4 * t + 2], uu.z, c1a);
      c1b = fdot2f(ktb[4 * t + 3], uu.w, c1b);
    }
    float v0n = rcpf_(c0a + c0b);
    float v1n = rcpf_(c1a + c1b);
    float m2 = fabsf(v0n - vo0) - TOL * v0n;
    float m3 = fabsf(v1n - vo1) - TOL * v1n;
    vo0 = v0n; vo1 = v1n;
    vhs[l] = pk2(v0n, v1n);
    float sv = v0n + v1n;
    sv += __shfl_xor(sv, 1);  sv += __shfl_xor(sv, 2);
    sv += __shfl_xor(sv, 4);  sv += __shfl_xor(sv, 8);
    sv += __shfl_xor(sv, 16); sv += __shfl_xor(sv, 32);
    sum_v = sv + v128n;
    v128 = v128n;
    // convergence (uniform after butterfly)
    float m = fmaxf(m1, fmaxf(m2, m3));
    m = fmaxf(m, __shfl_xor(m, 1));  m = fmaxf(m, __shfl_xor(m, 2));
    m = fmaxf(m, __shfl_xor(m, 4));  m = fmaxf(m, __shfl_xor(m, 8));
    m = fmaxf(m, __shfl_xor(m, 16)); m = fmaxf(m, __shfl_xor(m, 32));
    if (m <= 0.0f) break;
  }

  // ---- Phase 3: P[l][n] = K*u*v -> bf16 ----
  {
    unsigned short* Pout = Pbuf + ((size_t)(s * B_ + b)) * (MM * NN);
    uint4* P4 = reinterpret_cast<uint4*>(Pout);
    const uint4* vh4 = reinterpret_cast<const uint4*>(vhs);
    #pragma unroll
    for (int t = 0; t < 16; ++t) {
      uint4 vv = vh4[t];
      u32 o0, o1, o2, o3;
#define PDW(KD, VD, OUT) do {                                                 \
      float p0 = h_lo(KD) * ur * h_lo(VD);                                    \
      float p1 = h_hi(KD) * ur * h_hi(VD);                                    \
      OUT = (u32)f2bf(p0) | ((u32)f2bf(p1) << 16);                            \
    } while (0)
      PDW(kr[4 * t + 0], vv.x, o0);
      PDW(kr[4 * t + 1], vv.y, o1);
      PDW(kr[4 * t + 2], vv.z, o2);
      PDW(kr[4 * t + 3], vv.w, o3);
#undef PDW
      P4[l * 16 + t] = make_uint4(o0, o1, o2, o3);
    }
  }
}

// ---------------------------------------------------------------------------
// Kernel B: per batch. Pc = a*Ps + (1-a)*Pf; adj_al = Pc@adj; al2 = adj_al@Pc^T;
// LN1 -> lnadj (bf16). feats_al = Pc@xf; LN2 -> lnfeats (bf16). grid 2048.
// ---------------------------------------------------------------------------
#define PC_S 132
__launch_bounds__(256, 2)
__global__ void align_kernel(const unsigned short* __restrict__ Pbuf,
                             const float* __restrict__ adj,
                             const float* __restrict__ x,
                             const float* __restrict__ alpha_p,
                             const float* __restrict__ ln1g, const float* __restrict__ ln1b,
                             const float* __restrict__ ln2g, const float* __restrict__ ln2b,
                             unsigned short* __restrict__ lnadj,
                             unsigned short* __restrict__ lnfeats)
{
  __shared__ __align__(16) float Pc[64 * PC_S];
  __shared__ __align__(16) unsigned short AAl[64 * PC_S];
  __shared__ __align__(16) float chunk[16 * 128];
  __shared__ float red[16];
  __shared__ float stats[2];

  const int tid = threadIdx.x;
  const int b = blockIdx.x;
  const float a = 1.0f / (1.0f + __expf(-alpha_p[0]));

  const unsigned short* Ps = Pbuf + (size_t)b * (64 * 128);
  const unsigned short* Pf = Pbuf + ((size_t)B_ + b) * (64 * 128);
  for (int idx = tid; idx < 64 * 128; idx += 256) {
    int m = idx >> 7, c = idx & 127;
    Pc[m * PC_S + c] = a * bf2f(Ps[idx]) + (1.0f - a) * bf2f(Pf[idx]);
  }
  __syncthreads();

  // adj_al = Pc @ adj[b]  (64x128)
  {
    const int dg = (tid & 31) * 4;
    const int m0 = (tid >> 5) * 8;
    float ac[8][4];
    #pragma unroll
    for (int i = 0; i < 8; ++i)
      #pragma unroll
      for (int j = 0; j < 4; ++j) ac[i][j] = 0.0f;
    for (int n0 = 0; n0 < 128; n0 += 16) {
      __syncthreads();
      for (int i = tid; i < 16 * 128; i += 256) {
        int nn = i >> 7, d = i & 127;
        chunk[i] = adj[((size_t)b * NN + (n0 + nn)) * NN + d];
      }
      __syncthreads();
      #pragma unroll
      for (int nn = 0; nn < 16; ++nn) {
        const float4 av = *reinterpret_cast<const float4*>(&chunk[nn * 128 + dg]);
        #pragma unroll
        for (int mi = 0; mi < 8; ++mi) {
          float p = Pc[(m0 + mi) * PC_S + n0 + nn];
          ac[mi][0] += p * av.x; ac[mi][1] += p * av.y;
          ac[mi][2] += p * av.z; ac[mi][3] += p * av.w;
        }
      }
    }
    __syncthreads();
    #pragma unroll
    for (int mi = 0; mi < 8; ++mi) {
      ushort4 st;
      st.x = f2bf(ac[mi][0]); st.y = f2bf(ac[mi][1]);
      st.z = f2bf(ac[mi][2]); st.w = f2bf(ac[mi][3]);
      *reinterpret_cast<ushort4*>(&AAl[(m0 + mi) * PC_S + dg]) = st;
    }
  }
  __syncthreads();

  // al2[m][k] = sum_d adj_al[m][d] * Pc[k][d]; then LN1 over 4096
  {
    const int m0 = (tid >> 4) * 4;
    const int k0 = (tid & 15) * 4;
    float c2[4][4];
    #pragma unroll
    for (int i = 0; i < 4; ++i)
      #pragma unroll
      for (int j = 0; j < 4; ++j) c2[i][j] = 0.0f;
    for (int d = 0; d < 128; d += 4) {
      float4 pv[4];
      #pragma unroll
      for (int ki = 0; ki < 4; ++ki)
        pv[ki] = *reinterpret_cast<const float4*>(&Pc[(k0 + ki) * PC_S + d]);
      #pragma unroll
      for (int mi = 0; mi < 4; ++mi) {
        ushort4 us = *reinterpret_cast<const ushort4*>(&AAl[(m0 + mi) * PC_S + d]);
        float a0 = bf2f(us.x), a1 = bf2f(us.y), a2 = bf2f(us.z), a3 = bf2f(us.w);
        #pragma unroll
        for (int ki = 0; ki < 4; ++ki)
          c2[mi][ki] += a0 * pv[ki].x + a1 * pv[ki].y + a2 * pv[ki].z + a3 * pv[ki].w;
      }
    }
    float lsum = 0.f, lsq = 0.f;
    #pragma unroll
    for (int mi = 0; mi < 4; ++mi)
      #pragma unroll
      for (int ki = 0; ki < 4; ++ki) { lsum += c2[mi][ki]; lsq += c2[mi][ki] * c2[mi][ki]; }
    for (int off = 32; off; off >>= 1) { lsum += __shfl_down(lsum, off); lsq += __shfl_down(lsq, off); }
    int wv = tid >> 6;
    if ((tid & 63) == 0) { red[wv] = lsum; red[8 + wv] = lsq; }
    __syncthreads();
    if (tid == 0) {
      float s0 = red[0] + red[1] + red[2] + red[3];
      float s1 = red[8] + red[9] + red[10] + red[11];
      float mean = s0 / 4096.0f;
      float var = s1 / 4096.0f - mean * mean;
      stats[0] = mean; stats[1] = rsqrtf(var + 1e-5f);
    }
    __syncthreads();
    float mean = stats[0], rstd = stats[1];
    #pragma unroll
    for (int mi = 0; mi < 4; ++mi)
      #pragma unroll
      for (int ki = 0; ki < 4; ++ki) {
        int pos = (m0 + mi) * 64 + (k0 + ki);
        float vv = (c2[mi][ki] - mean) * rstd * ln1g[pos] + ln1b[pos];
        lnadj[(size_t)b * 4096 + pos] = f2bf(vv);
      }
  }
  __syncthreads();

  // feats_al = Pc @ xf (64x16); LN2 over 1024
  for (int i = tid; i < 128 * 16; i += 256) {
    int nn = i >> 4, f = i & 15;
    chunk[i] = x[((size_t)b * NN + nn) * IND + 2 + f];
  }
  __syncthreads();
  {
    const int m = tid >> 2;
    const int f0 = (tid & 3) * 4;
    float c3[4] = {0.f, 0.f, 0.f, 0.f};
    for (int nn = 0; nn < 128; ++nn) {
      float p = Pc[m * PC_S + nn];
      const float4 xv = *reinterpret_cast<const float4*>(&chunk[nn * 16 + f0]);
      c3[0] += p * xv.x; c3[1] += p * xv.y; c3[2] += p * xv.z; c3[3] += p * xv.w;
    }
    float lsum = c3[0] + c3[1] + c3[2] + c3[3];
    float lsq = c3[0]*c3[0] + c3[1]*c3[1] + c3[2]*c3[2] + c3[3]*c3[3];
    for (int off = 32; off; off >>= 1) { lsum += __shfl_down(lsum, off); lsq += __shfl_down(lsq, off); }
    int wv = tid >> 6;
    if ((tid & 63) == 0) { red[wv] = lsum; red[8 + wv] = lsq; }
    __syncthreads();
    if (tid == 0) {
      float s0 = red[0] + red[1] + red[2] + red[3];
      float s1 = red[8] + red[9] + red[10] + red[11];
      float mean = s0 / 1024.0f;
      float var = s1 / 1024.0f - mean * mean;
      stats[0] = mean; stats[1] = rsqrtf(var + 1e-5f);
    }
    __syncthreads();
    float mean = stats[0], rstd = stats[1];
    #pragma unroll
    for (int j = 0; j < 4; ++j) {
      int pos = m * 16 + f0 + j;
      float vv = (c3[j] - mean) * rstd * ln2g[pos] + ln2b[pos];
      lnfeats[(size_t)b * 1024 + pos] = f2bf(vv);
    }
  }
}

// ---------------------------------------------------------------------------
// Kernel C: C[M][ldc] (+coff) = relu(A_bf16[M][K] @ W[N][K]^T + bias). Tiles 64x32.
// ---------------------------------------------------------------------------
__launch_bounds__(256)
__global__ void gemm_bf16_kernel(const unsigned short* __restrict__ A,
                                 const float* __restrict__ W,
                                 const float* __restrict__ bias,
                                 float* __restrict__ C,
                                 int M, int N, int K, int ldc, int coff)
{
  __shared__ __align__(16) float At[16][68];
  __shared__ __align__(16) float Wt[16][36];
  const int tid = threadIdx.x;
  const int m0g = blockIdx.x * 64;
  const int n0g = blockIdx.y * 32;
  const int mi0 = (tid >> 4) * 4;
  const int ni0 = (tid & 15) * 2;
  float acc[4][2];
  #pragma unroll
  for (int i = 0; i < 4; ++i) { acc[i][0] = 0.f; acc[i][1] = 0.f; }

  for (int kc = 0; kc < K; kc += 16) {
    __syncthreads();
    {
      int r = tid >> 2, ko = (tid & 3) * 4;
      const ushort4 us = *reinterpret_cast<const ushort4*>(&A[(size_t)(m0g + r) * K + kc + ko]);
      At[ko + 0][r] = bf2f(us.x); At[ko + 1][r] = bf2f(us.y);
      At[ko + 2][r] = bf2f(us.z); At[ko + 3][r] = bf2f(us.w);
    }
    {
      int r = tid >> 3, ko = (tid & 7) * 2;
      const float2 wv = *reinterpret_cast<const float2*>(&W[(size_t)(n0g + r) * K + kc + ko]);
      Wt[ko][r] = wv.x; Wt[ko + 1][r] = wv.y;
    }
    __syncthreads();
    #pragma unroll
    for (int kk = 0; kk < 16; ++kk) {
      const float4 av = *reinterpret_cast<const float4*>(&At[kk][mi0]);
      const float2 wv = *reinterpret_cast<const float2*>(&Wt[kk][ni0]);
      acc[0][0] += av.x * wv.x; acc[0][1] += av.x * wv.y;
      acc[1][0] += av.y * wv.x; acc[1][1] += av.y * wv.y;
      acc[2][0] += av.z * wv.x; acc[2][1] += av.z * wv.y;
      acc[3][0] += av.w * wv.x; acc[3][1] += av.w * wv.y;
    }
  }
  #pragma unroll
  for (int j = 0; j < 2; ++j) {
    float bb = bias[n0g + ni0 + j];
    #pragma unroll
    for (int i = 0; i < 4; ++i) {
      float vv = fmaxf(acc[i][j] + bb, 0.0f);
      C[(size_t)(m0g + mi0 + i) * ldc + coff + n0g + ni0 + j] = vv;
    }
  }
}

// ---------------------------------------------------------------------------
// Kernel D: per 4 rows: fc6(relu) -> fc7 -> log_softmax. grid 512, block 256.
// ---------------------------------------------------------------------------
__launch_bounds__(256)
__global__ void head_kernel(const float* __restrict__ h45,
                            const float* __restrict__ wT6,   // [512][64]
                            const float* __restrict__ b6,
                            const float* __restrict__ w7,    // [10][64]
                            const float* __restrict__ b7,
                            float* __restrict__ out)
{
  __shared__ float row[4][512];
  __shared__ float h6[4][64];
  const int tid = threadIdx.x;
  const int r0 = blockIdx.x * 4;
  for (int i = tid; i < 4 * 512; i += 256)
    row[i >> 9][i & 511] = h45[(size_t)(r0 + (i >> 9)) * 512 + (i & 511)];
  __syncthreads();
  const int r = tid >> 6, o = tid & 63;
  float accv = b6[o];
  #pragma unroll 8
  for (int k = 0; k < 512; ++k) accv += row[r][k] * wT6[k * 64 + o];
  h6[r][o] = fmaxf(accv, 0.0f);
  __syncthreads();
  float z = -1e30f;
  if (o < 10) {
    float a2 = b7[o];
    #pragma unroll
    for (int k = 0; k < 64; ++k) a2 += h6[r][k] * w7[o * 64 + k];
    z = a2;
  }
  float zs[10];
  #pragma unroll
  for (int j = 0; j < 10; ++j) zs[j] = __shfl(z, j, 64);
  float mx = zs[0];
  #pragma unroll
  for (int j = 1; j < 10; ++j) mx = fmaxf(mx, zs[j]);
  float se = 0.f;
  #pragma unroll
  for (int j = 0; j < 10; ++j) se += __expf(zs[j] - mx);
  if (o < 10) out[(size_t)(r0 + r) * 10 + o] = z - mx - __logf(se);
}

__global__ void transpose_kernel(const float* __restrict__ in, float* __restrict__ outp,
                                 int R, int Cc)
{
  int idx = blockIdx.x * blockDim.x + threadIdx.x;
  int total = R * Cc;
  for (; idx < total; idx += gridDim.x * blockDim.x) {
    int rr = idx / Cc, cc = idx - rr * Cc;
    outp[cc * R + rr] = in[idx];
  }
}

// ---------------------------------------------------------------------------
extern "C" void kernel_launch(void* const* d_in, const int* in_sizes, int n_in,
                              void* d_out, int out_size, void* d_ws, size_t ws_size,
                              hipStream_t stream)
{
  (void)in_sizes; (void)n_in; (void)out_size; (void)ws_size;
  const float* x    = (const float*)d_in[0];
  const float* adj  = (const float*)d_in[1];
  const float* w1   = (const float*)d_in[2];
  const float* w2   = (const float*)d_in[3];
  const float* alpha = (const float*)d_in[4];
  const float* bin_score = (const float*)d_in[5];
  const float* fc2w = (const float*)d_in[6];
  const float* fc2b = (const float*)d_in[7];
  const float* fc3w = (const float*)d_in[8];
  const float* fc3b = (const float*)d_in[9];
  const float* ln1g = (const float*)d_in[10];
  const float* ln1b = (const float*)d_in[11];
  const float* fc4w = (const float*)d_in[12];
  const float* fc4b = (const float*)d_in[13];
  const float* ln2g = (const float*)d_in[14];
  const float* ln2b = (const float*)d_in[15];
  const float* fc5w = (const float*)d_in[16];
  const float* fc5b = (const float*)d_in[17];
  const float* fc6w = (const float*)d_in[18];
  const float* fc6b = (const float*)d_in[19];
  const float* fc7w = (const float*)d_in[20];
  const float* fc7b = (const float*)d_in[21];
  float* out = (float*)d_out;

  char* ws = (char*)d_ws;
  unsigned short* Pbuf = (unsigned short*)ws;                       // 4096*8192 bf16 = 64 MB
  size_t off = (size_t)4096 * 8192 * 2;
  unsigned short* lnadj = (unsigned short*)(ws + off);  off += (size_t)2048 * 4096 * 2;
  unsigned short* lnfeats = (unsigned short*)(ws + off); off += (size_t)2048 * 1024 * 2;
  float* h45 = (float*)(ws + off);                      off += (size_t)2048 * 512 * 4;
  float* wT6 = (float*)(ws + off);                      off += (size_t)512 * 64 * 4;

  hipLaunchKernelGGL(ot_kernel, dim3(2048, 2), dim3(64), 0, stream,
                     x, w1, w2, fc2w, fc2b, fc3w, fc3b, bin_score, Pbuf);
  hipLaunchKernelGGL(transpose_kernel, dim3(32), dim3(256), 0, stream, fc6w, wT6, 64, 512);
  hipLaunchKernelGGL(align_kernel, dim3(2048), dim3(256), 0, stream,
                     Pbuf, adj, x, alpha, ln1g, ln1b, ln2g, ln2b, lnadj, lnfeats);
  hipLaunchKernelGGL(gemm_bf16_kernel, dim3(32, 8), dim3(256), 0, stream,
                     lnadj, fc4w, fc4b, h45, 2048, 256, 4096, 512, 0);
  hipLaunchKernelGGL(gemm_bf16_kernel, dim3(32, 8), dim3(256), 0, stream,
                     lnfeats, fc5w, fc5b, h45, 2048, 256, 1024, 512, 256);
  hipLaunchKernelGGL(head_kernel, dim3(512), dim3(256), 0, stream,
                     h45, wT6, fc6b, fc7w, fc7b, out);
}

// Round 4
// 435.811 us; speedup vs baseline: 1.8966x; 1.2364x over previous
//
#include <hip/hip_runtime.h>
#include <hip/hip_bf16.h>
#include <hip/hip_fp16.h>

// Problem constants
#define B_   2048
#define NN   128    // NMAX
#define MM   64     // HN
#define HD_  128
#define IND  18
#define FD_  16

typedef unsigned int u32;
typedef _Float16 h2_t __attribute__((ext_vector_type(2)));
typedef __attribute__((ext_vector_type(8))) short bf16x8;
typedef __attribute__((ext_vector_type(4))) float f32x4;

__device__ __forceinline__ float fdot2f(u32 a, u32 b, float c) {
#if defined(__has_builtin)
#if __has_builtin(__builtin_amdgcn_fdot2)
  return __builtin_amdgcn_fdot2(__builtin_bit_cast(h2_t, a),
                                __builtin_bit_cast(h2_t, b), c, false);
#else
  h2_t x = __builtin_bit_cast(h2_t, a), y = __builtin_bit_cast(h2_t, b);
  return c + (float)x[0] * (float)y[0] + (float)x[1] * (float)y[1];
#endif
#else
  h2_t x = __builtin_bit_cast(h2_t, a), y = __builtin_bit_cast(h2_t, b);
  return c + (float)x[0] * (float)y[0] + (float)x[1] * (float)y[1];
#endif
}

__device__ __forceinline__ u32 pk2(float a, float b) {
#if defined(__has_builtin)
#if __has_builtin(__builtin_amdgcn_cvt_pkrtz)
  return __builtin_bit_cast(u32, __builtin_amdgcn_cvt_pkrtz(a, b));
#else
  __half ha = __float2half_rn(a), hb = __float2half_rn(b);
  return (u32)__half_as_ushort(ha) | ((u32)__half_as_ushort(hb) << 16);
#endif
#else
  __half ha = __float2half_rn(a), hb = __float2half_rn(b);
  return (u32)__half_as_ushort(ha) | ((u32)__half_as_ushort(hb) << 16);
#endif
}

__device__ __forceinline__ float rcpf_(float x) {
#if defined(__has_builtin)
#if __has_builtin(__builtin_amdgcn_rcpf)
  return __builtin_amdgcn_rcpf(x);
#else
  return 1.0f / x;
#endif
#else
  return 1.0f / x;
#endif
}

__device__ __forceinline__ float h_lo(u32 d) {
  return __half2float(__ushort_as_half((unsigned short)(d & 0xffffu)));
}
__device__ __forceinline__ float h_hi(u32 d) {
  return __half2float(__ushort_as_half((unsigned short)(d >> 16)));
}

__device__ __forceinline__ float bf2f(unsigned short u) {
  union { float f; u32 i; } z; z.i = ((u32)u) << 16; return z.f;
}
__device__ __forceinline__ unsigned short f2bf(float f) {
  union { float fv; u32 u; } z; z.fv = f;
  u32 lsb = (z.u >> 16) & 1u;
  return (unsigned short)((z.u + 0x7fffu + lsb) >> 16);
}

// ---------------------------------------------------------------------------
// Kernel A: ONE WAVE per (batch, stream) OT problem. grid (2048,2), block 64.
// (unchanged from R3 — passed, ~<200us)
// ---------------------------------------------------------------------------
__launch_bounds__(64, 2)
__global__ void ot_kernel(const float* __restrict__ x,
                          const float* __restrict__ w1,
                          const float* __restrict__ w2,
                          const float* __restrict__ fc2w, const float* __restrict__ fc2b,
                          const float* __restrict__ fc3w, const float* __restrict__ fc3b,
                          const float* __restrict__ bin_score,
                          unsigned short* __restrict__ Pbuf)
{
  __shared__ __align__(16) u32 Ksh[64 * 68];      // 64 rows, pitch 68 dwords (136 f16)
  __shared__ __align__(16) u32 acteb[2][64];      // even-node act row (double buffer)
  __shared__ __align__(16) u32 actob[2][64];      // odd-node act row
  __shared__ __align__(16) u32 vhs[64];           // v[0..127] packed f16 pairs
  __shared__ __align__(16) u32 uhs[32];           // u[0..63] packed f16 pairs

  const int l = threadIdx.x;
  const int b = blockIdx.x, s = blockIdx.y;
  const float* wm = s ? w2 : w1;
  const float* fw = s ? fc3w : fc2w;
  const float* fb = s ? fc3b : fc2b;
  const int xoff = s ? 2 : 0;

  u32 fcwh[16];
  float bia0 = fb[2 * l], bia1 = fb[2 * l + 1];
  if (s) {
    const float* fr0 = fw + (size_t)(2 * l) * 16;
    const float* fr1 = fr0 + 16;
    #pragma unroll
    for (int j = 0; j < 8; ++j) {
      float2 a = *reinterpret_cast<const float2*>(fr0 + 2 * j);
      float2 c = *reinterpret_cast<const float2*>(fr1 + 2 * j);
      fcwh[j] = pk2(a.x, a.y);
      fcwh[8 + j] = pk2(c.x, c.y);
    }
  } else {
    #pragma unroll
    for (int j = 0; j < 16; ++j) fcwh[j] = 0u;
    fcwh[0] = pk2(fw[(2 * l) * 2], fw[(2 * l) * 2 + 1]);
    fcwh[8] = pk2(fw[(2 * l + 1) * 2], fw[(2 * l + 1) * 2 + 1]);
  }
  u32 xh[16];
  {
    const float* xr0 = x + ((size_t)b * NN + 2 * l) * IND + xoff;
    const float* xr1 = xr0 + IND;
    if (s) {
      #pragma unroll
      for (int j = 0; j < 8; ++j) {
        float2 a = *reinterpret_cast<const float2*>(xr0 + 2 * j);
        float2 c = *reinterpret_cast<const float2*>(xr1 + 2 * j);
        xh[j] = pk2(a.x, a.y);
        xh[8 + j] = pk2(c.x, c.y);
      }
    } else {
      #pragma unroll
      for (int j = 0; j < 16; ++j) xh[j] = 0u;
      xh[0] = pk2(xr0[0], xr0[1]);
      xh[8] = pk2(xr1[0], xr1[1]);
    }
  }
  u32 wreg[64];
  {
    const float* wr = wm + (size_t)l * 128;
    #pragma unroll
    for (int k = 0; k < 32; ++k) {
      float4 wv = *reinterpret_cast<const float4*>(wr + 4 * k);
      wreg[2 * k] = pk2(wv.x, wv.y);
      wreg[2 * k + 1] = pk2(wv.z, wv.w);
    }
  }
  const float ebs = __expf(bin_score[0]);

#define ACT_PAIR(NP, PB) do {                                                 \
    float ae0 = bia0, ae1 = bia1, ao0 = bia0, ao1 = bia1;                     \
    _Pragma("unroll")                                                         \
    for (int j = 0; j < 8; ++j) {                                             \
      u32 xe = __shfl(xh[j], (NP));                                           \
      u32 xo = __shfl(xh[8 + j], (NP));                                       \
      ae0 = fdot2f(fcwh[j], xe, ae0);                                         \
      ae1 = fdot2f(fcwh[8 + j], xe, ae1);                                     \
      ao0 = fdot2f(fcwh[j], xo, ao0);                                         \
      ao1 = fdot2f(fcwh[8 + j], xo, ao1);                                     \
    }                                                                         \
    acteb[(PB)][l] = pk2(fmaxf(ae0, 0.f), fmaxf(ae1, 0.f));                   \
    actob[(PB)][l] = pk2(fmaxf(ao0, 0.f), fmaxf(ao1, 0.f));                   \
  } while (0)

  ACT_PAIR(0, 0);
  for (int np = 0; np < 64; ++np) {
    const int pb = np & 1;
    if (np < 63) { ACT_PAIR(np + 1, (np + 1) & 1); }
    const uint4* ae4 = reinterpret_cast<const uint4*>(acteb[pb]);
    const uint4* ao4 = reinterpret_cast<const uint4*>(actob[pb]);
    float se0 = 0, se1 = 0, se2 = 0, se3 = 0;
    float so0 = 0, so1 = 0, so2 = 0, so3 = 0;
    #pragma unroll
    for (int t = 0; t < 16; ++t) {
      uint4 av = ae4[t];
      uint4 bv = ao4[t];
      se0 = fdot2f(wreg[4 * t + 0], av.x, se0);
      se1 = fdot2f(wreg[4 * t + 1], av.y, se1);
      se2 = fdot2f(wreg[4 * t + 2], av.z, se2);
      se3 = fdot2f(wreg[4 * t + 3], av.w, se3);
      so0 = fdot2f(wreg[4 * t + 0], bv.x, so0);
      so1 = fdot2f(wreg[4 * t + 1], bv.y, so1);
      so2 = fdot2f(wreg[4 * t + 2], bv.z, so2);
      so3 = fdot2f(wreg[4 * t + 3], bv.w, so3);
    }
    float ke = fminf(__expf(fmaxf((se0 + se1) + (se2 + se3), 0.f)), 60000.f);
    float ko = fminf(__expf(fmaxf((so0 + so1) + (so2 + so3), 0.f)), 60000.f);
    Ksh[l * 68 + np] = pk2(ke, ko);
  }
#undef ACT_PAIR

  u32 kr[64];
  #pragma unroll
  for (int t = 0; t < 16; ++t) {
    uint4 kv = *reinterpret_cast<const uint4*>(Ksh + l * 68 + 4 * t);
    kr[4 * t + 0] = kv.x; kr[4 * t + 1] = kv.y;
    kr[4 * t + 2] = kv.z; kr[4 * t + 3] = kv.w;
  }
  u32 kta[32], ktb[32];
  #pragma unroll
  for (int j = 0; j < 32; ++j) {
    u32 d0 = Ksh[(2 * j) * 68 + l];
    u32 d1 = Ksh[(2 * j + 1) * 68 + l];
    kta[j] = (d0 & 0xffffu) | (d1 << 16);
    ktb[j] = (d0 >> 16) | (d1 & 0xffff0000u);
  }

  vhs[l] = 0x3C003C00u;
  float v128 = 1.0f, sum_v = 129.0f;
  float u_old = 0.0f, vo0 = 1.0f, vo1 = 1.0f;
  float ur = 0.0f;
  const float TOL = 1e-4f;

  for (int it = 0; it < 100; ++it) {
    const float u64v = 128.0f * rcpf_(ebs * sum_v);
    float a0 = ebs * v128, a1 = 0.f, a2 = 0.f, a3 = 0.f;
    const uint4* vh4 = reinterpret_cast<const uint4*>(vhs);
    #pragma unroll
    for (int t = 0; t < 16; ++t) {
      uint4 vv = vh4[t];
      a0 = fdot2f(kr[4 * t + 0], vv.x, a0);
      a1 = fdot2f(kr[4 * t + 1], vv.y, a1);
      a2 = fdot2f(kr[4 * t + 2], vv.z, a2);
      a3 = fdot2f(kr[4 * t + 3], vv.w, a3);
    }
    float urn = rcpf_((a0 + a1) + (a2 + a3));
    float m1 = fabsf(urn - u_old) - TOL * urn;
    u_old = urn; ur = urn;
    float su = urn;
    su += __shfl_xor(su, 1);  su += __shfl_xor(su, 2);
    su += __shfl_xor(su, 4);  su += __shfl_xor(su, 8);
    su += __shfl_xor(su, 16); su += __shfl_xor(su, 32);
    const float sum_u = su + u64v;
    const float v128n = 64.0f * rcpf_(ebs * sum_u);
    float upr = __shfl_xor(urn, 1);
    if (!(l & 1)) uhs[l >> 1] = pk2(urn, upr);
    float c0a = ebs * u64v, c0b = 0.f, c1a = ebs * u64v, c1b = 0.f;
    const uint4* uh4 = reinterpret_cast<const uint4*>(uhs);
    #pragma unroll
    for (int t = 0; t < 8; ++t) {
      uint4 uu = uh4[t];
      c0a = fdot2f(kta[4 * t + 0], uu.x, c0a);
      c0b = fdot2f(kta[4 * t + 1], uu.y, c0b);
      c0a = fdot2f(kta[4 * t + 2], uu.z, c0a);
      c0b = fdot2f(kta[4 * t + 3], uu.w, c0b);
      c1a = fdot2f(ktb[4 * t + 0], uu.x, c1a);
      c1b = fdot2f(ktb[4 * t + 1], uu.y, c1b);
      c1a = fdot2f(ktb[4 * t + 2], uu.z, c1a);
      c1b = fdot2f(ktb[4 * t + 3], uu.w, c1b);
    }
    float v0n = rcpf_(c0a + c0b);
    float v1n = rcpf_(c1a + c1b);
    float m2 = fabsf(v0n - vo0) - TOL * v0n;
    float m3 = fabsf(v1n - vo1) - TOL * v1n;
    vo0 = v0n; vo1 = v1n;
    vhs[l] = pk2(v0n, v1n);
    float sv = v0n + v1n;
    sv += __shfl_xor(sv, 1);  sv += __shfl_xor(sv, 2);
    sv += __shfl_xor(sv, 4);  sv += __shfl_xor(sv, 8);
    sv += __shfl_xor(sv, 16); sv += __shfl_xor(sv, 32);
    sum_v = sv + v128n;
    v128 = v128n;
    float m = fmaxf(m1, fmaxf(m2, m3));
    m = fmaxf(m, __shfl_xor(m, 1));  m = fmaxf(m, __shfl_xor(m, 2));
    m = fmaxf(m, __shfl_xor(m, 4));  m = fmaxf(m, __shfl_xor(m, 8));
    m = fmaxf(m, __shfl_xor(m, 16)); m = fmaxf(m, __shfl_xor(m, 32));
    if (m <= 0.0f) break;
  }

  {
    unsigned short* Pout = Pbuf + ((size_t)(s * B_ + b)) * (MM * NN);
    uint4* P4 = reinterpret_cast<uint4*>(Pout);
    const uint4* vh4 = reinterpret_cast<const uint4*>(vhs);
    #pragma unroll
    for (int t = 0; t < 16; ++t) {
      uint4 vv = vh4[t];
      u32 o0, o1, o2, o3;
#define PDW(KD, VD, OUT) do {                                                 \
      float p0 = h_lo(KD) * ur * h_lo(VD);                                    \
      float p1 = h_hi(KD) * ur * h_hi(VD);                                    \
      OUT = (u32)f2bf(p0) | ((u32)f2bf(p1) << 16);                            \
    } while (0)
      PDW(kr[4 * t + 0], vv.x, o0);
      PDW(kr[4 * t + 1], vv.y, o1);
      PDW(kr[4 * t + 2], vv.z, o2);
      PDW(kr[4 * t + 3], vv.w, o3);
#undef PDW
      P4[l * 16 + t] = make_uint4(o0, o1, o2, o3);
    }
  }
}

// ---------------------------------------------------------------------------
// Kernel B (MFMA rewrite): per batch b.
//   Pm = a*Ps + (1-a)*Pf              (bf16 LDS, rows of 128)
//   Z1 = adj @ Pm^T (128x64), stored transposed Z1T[64][128] (bf16, free
//        transpose via MFMA D-layout lane-contiguous rows)
//   al2 = Pm @ Z1 (64x64)  [== (Pm@adj)@Pm^T by associativity]
//   feats = Pm @ xf (64x16)
//   LN1(al2) -> lnadj bf16; LN2(feats) -> lnfeats bf16.
// All MFMA A/B fragments are contiguous 16B row reads: lane&15 = row,
// lane>>4 = k-octet. grid 2048, block 256 (4 waves).
// ---------------------------------------------------------------------------
#define AP 136   // bf16 row pitch (272 B, 16B-aligned)

__device__ __forceinline__ bf16x8 ldfrag(const unsigned short* p) {
  return __builtin_bit_cast(bf16x8, *reinterpret_cast<const uint4*>(p));
}
__device__ __forceinline__ u32 comb2(u32 ps, u32 pf, float a, float na) {
  float r0 = a * bf2f((unsigned short)(ps & 0xffffu)) + na * bf2f((unsigned short)(pf & 0xffffu));
  float r1 = a * bf2f((unsigned short)(ps >> 16)) + na * bf2f((unsigned short)(pf >> 16));
  return (u32)f2bf(r0) | ((u32)f2bf(r1) << 16);
}

__launch_bounds__(256, 2)
__global__ void align_kernel(const unsigned short* __restrict__ Pbuf,
                             const float* __restrict__ adj,
                             const float* __restrict__ x,
                             const float* __restrict__ alpha_p,
                             const float* __restrict__ ln1g, const float* __restrict__ ln1b,
                             const float* __restrict__ ln2g, const float* __restrict__ ln2b,
                             unsigned short* __restrict__ lnadj,
                             unsigned short* __restrict__ lnfeats)
{
  __shared__ __align__(16) unsigned short adjb[128 * AP];   // 34816 B
  __shared__ __align__(16) unsigned short Pms[64 * AP];     // 17408 B
  __shared__ __align__(16) unsigned short Z1T[64 * AP];     // 17408 B
  __shared__ __align__(16) unsigned short xfT[16 * AP];     // 4352 B
  __shared__ float red[16];

  const int tid = threadIdx.x;
  const int b = blockIdx.x;
  const int w = tid >> 6;          // wave 0..3
  const int lane = tid & 63;
  const int l15 = lane & 15;
  const int q = lane >> 4;         // k-octet / row-quad group
  const float a = 1.0f / (1.0f + __expf(-alpha_p[0]));
  const float na = 1.0f - a;

  // ---- stage adj -> bf16 (coalesced float4 reads) ----
  {
    const float4* src = reinterpret_cast<const float4*>(adj + (size_t)b * (NN * NN));
    for (int i = tid; i < 128 * 32; i += 256) {
      int row = i >> 5, c4 = i & 31;
      float4 v = src[i];
      u32 w0 = (u32)f2bf(v.x) | ((u32)f2bf(v.y) << 16);
      u32 w1 = (u32)f2bf(v.z) | ((u32)f2bf(v.w) << 16);
      *reinterpret_cast<uint2*>(&adjb[row * AP + c4 * 4]) = make_uint2(w0, w1);
    }
  }
  // ---- stage Pm = a*Ps + (1-a)*Pf ----
  {
    const uint4* Ps4 = reinterpret_cast<const uint4*>(Pbuf + (size_t)b * (MM * NN));
    const uint4* Pf4 = reinterpret_cast<const uint4*>(Pbuf + ((size_t)B_ + b) * (MM * NN));
    for (int i = tid; i < 64 * 16; i += 256) {
      int row = i >> 4, g = i & 15;
      uint4 sa = Ps4[i];
      uint4 fa = Pf4[i];
      uint4 o;
      o.x = comb2(sa.x, fa.x, a, na); o.y = comb2(sa.y, fa.y, a, na);
      o.z = comb2(sa.z, fa.z, a, na); o.w = comb2(sa.w, fa.w, a, na);
      *reinterpret_cast<uint4*>(&Pms[row * AP + g * 8]) = o;
    }
  }
  // ---- stage xfT[f][n] = x[b][n][2+f] ----
  for (int i = tid; i < 2048; i += 256) {
    int n = i & 127, f = i >> 7;
    xfT[f * AP + n] = f2bf(x[((size_t)b * NN + n) * IND + 2 + f]);
  }
  __syncthreads();

  // ---- M1: Z1[n][k] = sum_d adj[n][d]*Pm[k][d]; wave w owns n in [32w,32w+32) ----
  {
    f32x4 acc[2][4];
    #pragma unroll
    for (int i = 0; i < 2; ++i)
      #pragma unroll
      for (int j = 0; j < 4; ++j) acc[i][j] = f32x4{0.f, 0.f, 0.f, 0.f};
    #pragma unroll
    for (int kt = 0; kt < 4; ++kt) {
      const int d0 = 32 * kt + 8 * q;
      bf16x8 bf[4];
      #pragma unroll
      for (int j = 0; j < 4; ++j)
        bf[j] = ldfrag(&Pms[(16 * j + l15) * AP + d0]);
      #pragma unroll
      for (int ai = 0; ai < 2; ++ai) {
        bf16x8 af = ldfrag(&adjb[(32 * w + 16 * ai + l15) * AP + d0]);
        #pragma unroll
        for (int j = 0; j < 4; ++j)
          acc[ai][j] = __builtin_amdgcn_mfma_f32_16x16x32_bf16(af, bf[j], acc[ai][j], 0, 0, 0);
      }
    }
    // write Z1T[k][n]: lane holds col k=16j+l15, rows n = 32w+16ai+4q+r
    #pragma unroll
    for (int ai = 0; ai < 2; ++ai) {
      #pragma unroll
      for (int j = 0; j < 4; ++j) {
        const int k = 16 * j + l15;
        const int nbase = 32 * w + 16 * ai + 4 * q;
        u32 w0 = (u32)f2bf(acc[ai][j][0]) | ((u32)f2bf(acc[ai][j][1]) << 16);
        u32 w1 = (u32)f2bf(acc[ai][j][2]) | ((u32)f2bf(acc[ai][j][3]) << 16);
        *reinterpret_cast<uint2*>(&Z1T[k * AP + nbase]) = make_uint2(w0, w1);
      }
    }
  }
  __syncthreads();

  // ---- M2: al2[m][k] = sum_n Pm[m][n]*Z1[n][k]; M3: feats = Pm @ xf ----
  f32x4 acc2[4];
  f32x4 acc3 = f32x4{0.f, 0.f, 0.f, 0.f};
  #pragma unroll
  for (int j = 0; j < 4; ++j) acc2[j] = f32x4{0.f, 0.f, 0.f, 0.f};
  #pragma unroll
  for (int nt = 0; nt < 4; ++nt) {
    const int n0 = 32 * nt + 8 * q;
    bf16x8 af = ldfrag(&Pms[(16 * w + l15) * AP + n0]);
    #pragma unroll
    for (int j = 0; j < 4; ++j) {
      bf16x8 bv = ldfrag(&Z1T[(16 * j + l15) * AP + n0]);
      acc2[j] = __builtin_amdgcn_mfma_f32_16x16x32_bf16(af, bv, acc2[j], 0, 0, 0);
    }
    bf16x8 bx = ldfrag(&xfT[l15 * AP + n0]);
    acc3 = __builtin_amdgcn_mfma_f32_16x16x32_bf16(af, bx, acc3, 0, 0, 0);
  }

  // ---- LN reductions (LN1 over 4096 al2 vals, LN2 over 1024 feats vals) ----
  {
    float s1 = 0.f, q1 = 0.f, s2 = 0.f, q2 = 0.f;
    #pragma unroll
    for (int j = 0; j < 4; ++j)
      #pragma unroll
      for (int r = 0; r < 4; ++r) { float v = acc2[j][r]; s1 += v; q1 += v * v; }
    #pragma unroll
    for (int r = 0; r < 4; ++r) { float v = acc3[r]; s2 += v; q2 += v * v; }
    #pragma unroll
    for (int off = 1; off < 64; off <<= 1) {
      s1 += __shfl_xor(s1, off); q1 += __shfl_xor(q1, off);
      s2 += __shfl_xor(s2, off); q2 += __shfl_xor(q2, off);
    }
    if (lane == 0) { red[w] = s1; red[4 + w] = q1; red[8 + w] = s2; red[12 + w] = q2; }
  }
  __syncthreads();
  const float S1 = red[0] + red[1] + red[2] + red[3];
  const float Q1 = red[4] + red[5] + red[6] + red[7];
  const float S2 = red[8] + red[9] + red[10] + red[11];
  const float Q2 = red[12] + red[13] + red[14] + red[15];
  const float mean1 = S1 * (1.0f / 4096.0f);
  const float rstd1 = rsqrtf(Q1 * (1.0f / 4096.0f) - mean1 * mean1 + 1e-5f);
  const float mean2 = S2 * (1.0f / 1024.0f);
  const float rstd2 = rsqrtf(Q2 * (1.0f / 1024.0f) - mean2 * mean2 + 1e-5f);

  // ---- normalize + bounce through freed LDS (adjb, Z1T) for coalesced out ----
  unsigned short* ob1 = adjb;   // 4096 shorts
  unsigned short* ob2 = Z1T;    // 1024 shorts
  #pragma unroll
  for (int j = 0; j < 4; ++j) {
    const int k = 16 * j + l15;
    #pragma unroll
    for (int r = 0; r < 4; ++r) {
      const int m = 16 * w + 4 * q + r;
      const int pos = m * 64 + k;
      float vv = (acc2[j][r] - mean1) * rstd1 * ln1g[pos] + ln1b[pos];
      ob1[pos] = f2bf(vv);
    }
  }
  {
    const int f = l15;
    #pragma unroll
    for (int r = 0; r < 4; ++r) {
      const int m = 16 * w + 4 * q + r;
      const int pos = m * 16 + f;
      float vv = (acc3[r] - mean2) * rstd2 * ln2g[pos] + ln2b[pos];
      ob2[pos] = f2bf(vv);
    }
  }
  __syncthreads();
  {
    const uint4* sp = reinterpret_cast<const uint4*>(ob1);
    uint4* dp = reinterpret_cast<uint4*>(lnadj + (size_t)b * 4096);
    for (int i = tid; i < 512; i += 256) dp[i] = sp[i];
    if (tid < 128)
      reinterpret_cast<uint4*>(lnfeats + (size_t)b * 1024)[tid] =
          reinterpret_cast<const uint4*>(ob2)[tid];
  }
}

// ---------------------------------------------------------------------------
// Kernel C: C[M][ldc] (+coff) = relu(A_bf16[M][K] @ W[N][K]^T + bias). Tiles 64x32.
// ---------------------------------------------------------------------------
__launch_bounds__(256)
__global__ void gemm_bf16_kernel(const unsigned short* __restrict__ A,
                                 const float* __restrict__ W,
                                 const float* __restrict__ bias,
                                 float* __restrict__ C,
                                 int M, int N, int K, int ldc, int coff)
{
  __shared__ __align__(16) float At[16][68];
  __shared__ __align__(16) float Wt[16][36];
  const int tid = threadIdx.x;
  const int m0g = blockIdx.x * 64;
  const int n0g = blockIdx.y * 32;
  const int mi0 = (tid >> 4) * 4;
  const int ni0 = (tid & 15) * 2;
  float acc[4][2];
  #pragma unroll
  for (int i = 0; i < 4; ++i) { acc[i][0] = 0.f; acc[i][1] = 0.f; }

  for (int kc = 0; kc < K; kc += 16) {
    __syncthreads();
    {
      int r = tid >> 2, ko = (tid & 3) * 4;
      const ushort4 us = *reinterpret_cast<const ushort4*>(&A[(size_t)(m0g + r) * K + kc + ko]);
      At[ko + 0][r] = bf2f(us.x); At[ko + 1][r] = bf2f(us.y);
      At[ko + 2][r] = bf2f(us.z); At[ko + 3][r] = bf2f(us.w);
    }
    {
      int r = tid >> 3, ko = (tid & 7) * 2;
      const float2 wv = *reinterpret_cast<const float2*>(&W[(size_t)(n0g + r) * K + kc + ko]);
      Wt[ko][r] = wv.x; Wt[ko + 1][r] = wv.y;
    }
    __syncthreads();
    #pragma unroll
    for (int kk = 0; kk < 16; ++kk) {
      const float4 av = *reinterpret_cast<const float4*>(&At[kk][mi0]);
      const float2 wv = *reinterpret_cast<const float2*>(&Wt[kk][ni0]);
      acc[0][0] += av.x * wv.x; acc[0][1] += av.x * wv.y;
      acc[1][0] += av.y * wv.x; acc[1][1] += av.y * wv.y;
      acc[2][0] += av.z * wv.x; acc[2][1] += av.z * wv.y;
      acc[3][0] += av.w * wv.x; acc[3][1] += av.w * wv.y;
    }
  }
  #pragma unroll
  for (int j = 0; j < 2; ++j) {
    float bb = bias[n0g + ni0 + j];
    #pragma unroll
    for (int i = 0; i < 4; ++i) {
      float vv = fmaxf(acc[i][j] + bb, 0.0f);
      C[(size_t)(m0g + mi0 + i) * ldc + coff + n0g + ni0 + j] = vv;
    }
  }
}

// ---------------------------------------------------------------------------
// Kernel D: per 4 rows: fc6(relu) -> fc7 -> log_softmax. grid 512, block 256.
// ---------------------------------------------------------------------------
__launch_bounds__(256)
__global__ void head_kernel(const float* __restrict__ h45,
                            const float* __restrict__ wT6,   // [512][64]
                            const float* __restrict__ b6,
                            const float* __restrict__ w7,    // [10][64]
                            const float* __restrict__ b7,
                            float* __restrict__ out)
{
  __shared__ float row[4][512];
  __shared__ float h6[4][64];
  const int tid = threadIdx.x;
  const int r0 = blockIdx.x * 4;
  for (int i = tid; i < 4 * 512; i += 256)
    row[i >> 9][i & 511] = h45[(size_t)(r0 + (i >> 9)) * 512 + (i & 511)];
  __syncthreads();
  const int r = tid >> 6, o = tid & 63;
  float accv = b6[o];
  #pragma unroll 8
  for (int k = 0; k < 512; ++k) accv += row[r][k] * wT6[k * 64 + o];
  h6[r][o] = fmaxf(accv, 0.0f);
  __syncthreads();
  float z = -1e30f;
  if (o < 10) {
    float a2 = b7[o];
    #pragma unroll
    for (int k = 0; k < 64; ++k) a2 += h6[r][k] * w7[o * 64 + k];
    z = a2;
  }
  float zs[10];
  #pragma unroll
  for (int j = 0; j < 10; ++j) zs[j] = __shfl(z, j, 64);
  float mx = zs[0];
  #pragma unroll
  for (int j = 1; j < 10; ++j) mx = fmaxf(mx, zs[j]);
  float se = 0.f;
  #pragma unroll
  for (int j = 0; j < 10; ++j) se += __expf(zs[j] - mx);
  if (o < 10) out[(size_t)(r0 + r) * 10 + o] = z - mx - __logf(se);
}

__global__ void transpose_kernel(const float* __restrict__ in, float* __restrict__ outp,
                                 int R, int Cc)
{
  int idx = blockIdx.x * blockDim.x + threadIdx.x;
  int total = R * Cc;
  for (; idx < total; idx += gridDim.x * blockDim.x) {
    int rr = idx / Cc, cc = idx - rr * Cc;
    outp[cc * R + rr] = in[idx];
  }
}

// ---------------------------------------------------------------------------
extern "C" void kernel_launch(void* const* d_in, const int* in_sizes, int n_in,
                              void* d_out, int out_size, void* d_ws, size_t ws_size,
                              hipStream_t stream)
{
  (void)in_sizes; (void)n_in; (void)out_size; (void)ws_size;
  const float* x    = (const float*)d_in[0];
  const float* adj  = (const float*)d_in[1];
  const float* w1   = (const float*)d_in[2];
  const float* w2   = (const float*)d_in[3];
  const float* alpha = (const float*)d_in[4];
  const float* bin_score = (const float*)d_in[5];
  const float* fc2w = (const float*)d_in[6];
  const float* fc2b = (const float*)d_in[7];
  const float* fc3w = (const float*)d_in[8];
  const float* fc3b = (const float*)d_in[9];
  const float* ln1g = (const float*)d_in[10];
  const float* ln1b = (const float*)d_in[11];
  const float* fc4w = (const float*)d_in[12];
  const float* fc4b = (const float*)d_in[13];
  const float* ln2g = (const float*)d_in[14];
  const float* ln2b = (const float*)d_in[15];
  const float* fc5w = (const float*)d_in[16];
  const float* fc5b = (const float*)d_in[17];
  const float* fc6w = (const float*)d_in[18];
  const float* fc6b = (const float*)d_in[19];
  const float* fc7w = (const float*)d_in[20];
  const float* fc7b = (const float*)d_in[21];
  float* out = (float*)d_out;

  char* ws = (char*)d_ws;
  unsigned short* Pbuf = (unsigned short*)ws;                       // 4096*8192 bf16 = 64 MB
  size_t off = (size_t)4096 * 8192 * 2;
  unsigned short* lnadj = (unsigned short*)(ws + off);  off += (size_t)2048 * 4096 * 2;
  unsigned short* lnfeats = (unsigned short*)(ws + off); off += (size_t)2048 * 1024 * 2;
  float* h45 = (float*)(ws + off);                      off += (size_t)2048 * 512 * 4;
  float* wT6 = (float*)(ws + off);                      off += (size_t)512 * 64 * 4;

  hipLaunchKernelGGL(ot_kernel, dim3(2048, 2), dim3(64), 0, stream,
                     x, w1, w2, fc2w, fc2b, fc3w, fc3b, bin_score, Pbuf);
  hipLaunchKernelGGL(transpose_kernel, dim3(32), dim3(256), 0, stream, fc6w, wT6, 64, 512);
  hipLaunchKernelGGL(align_kernel, dim3(2048), dim3(256), 0, stream,
                     Pbuf, adj, x, alpha, ln1g, ln1b, ln2g, ln2b, lnadj, lnfeats);
  hipLaunchKernelGGL(gemm_bf16_kernel, dim3(32, 8), dim3(256), 0, stream,
                     lnadj, fc4w, fc4b, h45, 2048, 256, 4096, 512, 0);
  hipLaunchKernelGGL(gemm_bf16_kernel, dim3(32, 8), dim3(256), 0, stream,
                     lnfeats, fc5w, fc5b, h45, 2048, 256, 1024, 512, 256);
  hipLaunchKernelGGL(head_kernel, dim3(512), dim3(256), 0, stream,
                     h45, wT6, fc6b, fc7w, fc7b, out);
}

// Round 5
// 314.040 us; speedup vs baseline: 2.6321x; 1.3878x over previous
//
#include <hip/hip_runtime.h>
#include <hip/hip_bf16.h>
#include <hip/hip_fp16.h>

// Problem constants
#define B_   2048
#define NN   128    // NMAX
#define MM   64     // HN
#define HD_  128
#define IND  18
#define FD_  16

typedef unsigned int u32;
typedef _Float16 h2_t __attribute__((ext_vector_type(2)));
typedef __attribute__((ext_vector_type(8))) short bf16x8;
typedef __attribute__((ext_vector_type(4))) float f32x4;

__device__ __forceinline__ float fdot2f(u32 a, u32 b, float c) {
#if defined(__has_builtin)
#if __has_builtin(__builtin_amdgcn_fdot2)
  return __builtin_amdgcn_fdot2(__builtin_bit_cast(h2_t, a),
                                __builtin_bit_cast(h2_t, b), c, false);
#else
  h2_t x = __builtin_bit_cast(h2_t, a), y = __builtin_bit_cast(h2_t, b);
  return c + (float)x[0] * (float)y[0] + (float)x[1] * (float)y[1];
#endif
#else
  h2_t x = __builtin_bit_cast(h2_t, a), y = __builtin_bit_cast(h2_t, b);
  return c + (float)x[0] * (float)y[0] + (float)x[1] * (float)y[1];
#endif
}

__device__ __forceinline__ u32 pk2(float a, float b) {
#if defined(__has_builtin)
#if __has_builtin(__builtin_amdgcn_cvt_pkrtz)
  return __builtin_bit_cast(u32, __builtin_amdgcn_cvt_pkrtz(a, b));
#else
  __half ha = __float2half_rn(a), hb = __float2half_rn(b);
  return (u32)__half_as_ushort(ha) | ((u32)__half_as_ushort(hb) << 16);
#endif
#else
  __half ha = __float2half_rn(a), hb = __float2half_rn(b);
  return (u32)__half_as_ushort(ha) | ((u32)__half_as_ushort(hb) << 16);
#endif
}

__device__ __forceinline__ float rcpf_(float x) {
#if defined(__has_builtin)
#if __has_builtin(__builtin_amdgcn_rcpf)
  return __builtin_amdgcn_rcpf(x);
#else
  return 1.0f / x;
#endif
#else
  return 1.0f / x;
#endif
}

__device__ __forceinline__ float h_lo(u32 d) {
  return __half2float(__ushort_as_half((unsigned short)(d & 0xffffu)));
}
__device__ __forceinline__ float h_hi(u32 d) {
  return __half2float(__ushort_as_half((unsigned short)(d >> 16)));
}

__device__ __forceinline__ float bf2f(unsigned short u) {
  union { float f; u32 i; } z; z.i = ((u32)u) << 16; return z.f;
}
__device__ __forceinline__ unsigned short f2bf(float f) {
  union { float fv; u32 u; } z; z.fv = f;
  u32 lsb = (z.u >> 16) & 1u;
  return (unsigned short)((z.u + 0x7fffu + lsb) >> 16);
}

// ---------------------------------------------------------------------------
// Kernel A: ONE WAVE per (batch, stream) OT problem. grid (2048,2), block 64.
// Change vs R4: convergence reduce via __all, checked every 2nd iteration.
// ---------------------------------------------------------------------------
__launch_bounds__(64, 2)
__global__ void ot_kernel(const float* __restrict__ x,
                          const float* __restrict__ w1,
                          const float* __restrict__ w2,
                          const float* __restrict__ fc2w, const float* __restrict__ fc2b,
                          const float* __restrict__ fc3w, const float* __restrict__ fc3b,
                          const float* __restrict__ bin_score,
                          unsigned short* __restrict__ Pbuf)
{
  __shared__ __align__(16) u32 Ksh[64 * 68];      // 64 rows, pitch 68 dwords (136 f16)
  __shared__ __align__(16) u32 acteb[2][64];      // even-node act row (double buffer)
  __shared__ __align__(16) u32 actob[2][64];      // odd-node act row
  __shared__ __align__(16) u32 vhs[64];           // v[0..127] packed f16 pairs
  __shared__ __align__(16) u32 uhs[32];           // u[0..63] packed f16 pairs

  const int l = threadIdx.x;
  const int b = blockIdx.x, s = blockIdx.y;
  const float* wm = s ? w2 : w1;
  const float* fw = s ? fc3w : fc2w;
  const float* fb = s ? fc3b : fc2b;
  const int xoff = s ? 2 : 0;

  u32 fcwh[16];
  float bia0 = fb[2 * l], bia1 = fb[2 * l + 1];
  if (s) {
    const float* fr0 = fw + (size_t)(2 * l) * 16;
    const float* fr1 = fr0 + 16;
    #pragma unroll
    for (int j = 0; j < 8; ++j) {
      float2 a = *reinterpret_cast<const float2*>(fr0 + 2 * j);
      float2 c = *reinterpret_cast<const float2*>(fr1 + 2 * j);
      fcwh[j] = pk2(a.x, a.y);
      fcwh[8 + j] = pk2(c.x, c.y);
    }
  } else {
    #pragma unroll
    for (int j = 0; j < 16; ++j) fcwh[j] = 0u;
    fcwh[0] = pk2(fw[(2 * l) * 2], fw[(2 * l) * 2 + 1]);
    fcwh[8] = pk2(fw[(2 * l + 1) * 2], fw[(2 * l + 1) * 2 + 1]);
  }
  u32 xh[16];
  {
    const float* xr0 = x + ((size_t)b * NN + 2 * l) * IND + xoff;
    const float* xr1 = xr0 + IND;
    if (s) {
      #pragma unroll
      for (int j = 0; j < 8; ++j) {
        float2 a = *reinterpret_cast<const float2*>(xr0 + 2 * j);
        float2 c = *reinterpret_cast<const float2*>(xr1 + 2 * j);
        xh[j] = pk2(a.x, a.y);
        xh[8 + j] = pk2(c.x, c.y);
      }
    } else {
      #pragma unroll
      for (int j = 0; j < 16; ++j) xh[j] = 0u;
      xh[0] = pk2(xr0[0], xr0[1]);
      xh[8] = pk2(xr1[0], xr1[1]);
    }
  }
  u32 wreg[64];
  {
    const float* wr = wm + (size_t)l * 128;
    #pragma unroll
    for (int k = 0; k < 32; ++k) {
      float4 wv = *reinterpret_cast<const float4*>(wr + 4 * k);
      wreg[2 * k] = pk2(wv.x, wv.y);
      wreg[2 * k + 1] = pk2(wv.z, wv.w);
    }
  }
  const float ebs = __expf(bin_score[0]);

#define ACT_PAIR(NP, PB) do {                                                 \
    float ae0 = bia0, ae1 = bia1, ao0 = bia0, ao1 = bia1;                     \
    _Pragma("unroll")                                                         \
    for (int j = 0; j < 8; ++j) {                                             \
      u32 xe = __shfl(xh[j], (NP));                                           \
      u32 xo = __shfl(xh[8 + j], (NP));                                       \
      ae0 = fdot2f(fcwh[j], xe, ae0);                                         \
      ae1 = fdot2f(fcwh[8 + j], xe, ae1);                                     \
      ao0 = fdot2f(fcwh[j], xo, ao0);                                         \
      ao1 = fdot2f(fcwh[8 + j], xo, ao1);                                     \
    }                                                                         \
    acteb[(PB)][l] = pk2(fmaxf(ae0, 0.f), fmaxf(ae1, 0.f));                   \
    actob[(PB)][l] = pk2(fmaxf(ao0, 0.f), fmaxf(ao1, 0.f));                   \
  } while (0)

  ACT_PAIR(0, 0);
  for (int np = 0; np < 64; ++np) {
    const int pb = np & 1;
    if (np < 63) { ACT_PAIR(np + 1, (np + 1) & 1); }
    const uint4* ae4 = reinterpret_cast<const uint4*>(acteb[pb]);
    const uint4* ao4 = reinterpret_cast<const uint4*>(actob[pb]);
    float se0 = 0, se1 = 0, se2 = 0, se3 = 0;
    float so0 = 0, so1 = 0, so2 = 0, so3 = 0;
    #pragma unroll
    for (int t = 0; t < 16; ++t) {
      uint4 av = ae4[t];
      uint4 bv = ao4[t];
      se0 = fdot2f(wreg[4 * t + 0], av.x, se0);
      se1 = fdot2f(wreg[4 * t + 1], av.y, se1);
      se2 = fdot2f(wreg[4 * t + 2], av.z, se2);
      se3 = fdot2f(wreg[4 * t + 3], av.w, se3);
      so0 = fdot2f(wreg[4 * t + 0], bv.x, so0);
      so1 = fdot2f(wreg[4 * t + 1], bv.y, so1);
      so2 = fdot2f(wreg[4 * t + 2], bv.z, so2);
      so3 = fdot2f(wreg[4 * t + 3], bv.w, so3);
    }
    float ke = fminf(__expf(fmaxf((se0 + se1) + (se2 + se3), 0.f)), 60000.f);
    float ko = fminf(__expf(fmaxf((so0 + so1) + (so2 + so3), 0.f)), 60000.f);
    Ksh[l * 68 + np] = pk2(ke, ko);
  }
#undef ACT_PAIR

  u32 kr[64];
  #pragma unroll
  for (int t = 0; t < 16; ++t) {
    uint4 kv = *reinterpret_cast<const uint4*>(Ksh + l * 68 + 4 * t);
    kr[4 * t + 0] = kv.x; kr[4 * t + 1] = kv.y;
    kr[4 * t + 2] = kv.z; kr[4 * t + 3] = kv.w;
  }
  u32 kta[32], ktb[32];
  #pragma unroll
  for (int j = 0; j < 32; ++j) {
    u32 d0 = Ksh[(2 * j) * 68 + l];
    u32 d1 = Ksh[(2 * j + 1) * 68 + l];
    kta[j] = (d0 & 0xffffu) | (d1 << 16);
    ktb[j] = (d0 >> 16) | (d1 & 0xffff0000u);
  }

  vhs[l] = 0x3C003C00u;
  float v128 = 1.0f, sum_v = 129.0f;
  float u_old = 0.0f, vo0 = 1.0f, vo1 = 1.0f;
  float ur = 0.0f;
  const float TOL = 1e-4f;

  for (int it = 0; it < 100; ++it) {
    const float u64v = 128.0f * rcpf_(ebs * sum_v);
    float a0 = ebs * v128, a1 = 0.f, a2 = 0.f, a3 = 0.f;
    const uint4* vh4 = reinterpret_cast<const uint4*>(vhs);
    #pragma unroll
    for (int t = 0; t < 16; ++t) {
      uint4 vv = vh4[t];
      a0 = fdot2f(kr[4 * t + 0], vv.x, a0);
      a1 = fdot2f(kr[4 * t + 1], vv.y, a1);
      a2 = fdot2f(kr[4 * t + 2], vv.z, a2);
      a3 = fdot2f(kr[4 * t + 3], vv.w, a3);
    }
    float urn = rcpf_((a0 + a1) + (a2 + a3));
    float m1 = fabsf(urn - u_old) - TOL * urn;
    u_old = urn; ur = urn;
    float su = urn;
    su += __shfl_xor(su, 1);  su += __shfl_xor(su, 2);
    su += __shfl_xor(su, 4);  su += __shfl_xor(su, 8);
    su += __shfl_xor(su, 16); su += __shfl_xor(su, 32);
    const float sum_u = su + u64v;
    const float v128n = 64.0f * rcpf_(ebs * sum_u);
    float upr = __shfl_xor(urn, 1);
    if (!(l & 1)) uhs[l >> 1] = pk2(urn, upr);
    float c0a = ebs * u64v, c0b = 0.f, c1a = ebs * u64v, c1b = 0.f;
    const uint4* uh4 = reinterpret_cast<const uint4*>(uhs);
    #pragma unroll
    for (int t = 0; t < 8; ++t) {
      uint4 uu = uh4[t];
      c0a = fdot2f(kta[4 * t + 0], uu.x, c0a);
      c0b = fdot2f(kta[4 * t + 1], uu.y, c0b);
      c0a = fdot2f(kta[4 * t + 2], uu.z, c0a);
      c0b = fdot2f(kta[4 * t + 3], uu.w, c0b);
      c1a = fdot2f(ktb[4 * t + 0], uu.x, c1a);
      c1b = fdot2f(ktb[4 * t + 1], uu.y, c1b);
      c1a = fdot2f(ktb[4 * t + 2], uu.z, c1a);
      c1b = fdot2f(ktb[4 * t + 3], uu.w, c1b);
    }
    float v0n = rcpf_(c0a + c0b);
    float v1n = rcpf_(c1a + c1b);
    float m2 = fabsf(v0n - vo0) - TOL * v0n;
    float m3 = fabsf(v1n - vo1) - TOL * v1n;
    vo0 = v0n; vo1 = v1n;
    vhs[l] = pk2(v0n, v1n);
    float sv = v0n + v1n;
    sv += __shfl_xor(sv, 1);  sv += __shfl_xor(sv, 2);
    sv += __shfl_xor(sv, 4);  sv += __shfl_xor(sv, 8);
    sv += __shfl_xor(sv, 16); sv += __shfl_xor(sv, 32);
    sum_v = sv + v128n;
    v128 = v128n;
    // convergence: check every 2nd iteration, wave-vote instead of butterfly
    if (it & 1) {
      float mcond = fmaxf(m1, fmaxf(m2, m3));
      if (__all(mcond <= 0.0f)) break;
    }
  }

  {
    unsigned short* Pout = Pbuf + ((size_t)(s * B_ + b)) * (MM * NN);
    uint4* P4 = reinterpret_cast<uint4*>(Pout);
    const uint4* vh4 = reinterpret_cast<const uint4*>(vhs);
    #pragma unroll
    for (int t = 0; t < 16; ++t) {
      uint4 vv = vh4[t];
      u32 o0, o1, o2, o3;
#define PDW(KD, VD, OUT) do {                                                 \
      float p0 = h_lo(KD) * ur * h_lo(VD);                                    \
      float p1 = h_hi(KD) * ur * h_hi(VD);                                    \
      OUT = (u32)f2bf(p0) | ((u32)f2bf(p1) << 16);                            \
    } while (0)
      PDW(kr[4 * t + 0], vv.x, o0);
      PDW(kr[4 * t + 1], vv.y, o1);
      PDW(kr[4 * t + 2], vv.z, o2);
      PDW(kr[4 * t + 3], vv.w, o3);
#undef PDW
      P4[l * 16 + t] = make_uint4(o0, o1, o2, o3);
    }
  }
}

// ---------------------------------------------------------------------------
// Kernel B (MFMA): unchanged from R4 (passed, ~47us).
// ---------------------------------------------------------------------------
#define AP 136   // bf16 row pitch (272 B, 16B aligned)

__device__ __forceinline__ bf16x8 ldfrag(const unsigned short* p) {
  return __builtin_bit_cast(bf16x8, *reinterpret_cast<const uint4*>(p));
}
__device__ __forceinline__ u32 comb2(u32 ps, u32 pf, float a, float na) {
  float r0 = a * bf2f((unsigned short)(ps & 0xffffu)) + na * bf2f((unsigned short)(pf & 0xffffu));
  float r1 = a * bf2f((unsigned short)(ps >> 16)) + na * bf2f((unsigned short)(pf >> 16));
  return (u32)f2bf(r0) | ((u32)f2bf(r1) << 16);
}

__launch_bounds__(256, 2)
__global__ void align_kernel(const unsigned short* __restrict__ Pbuf,
                             const float* __restrict__ adj,
                             const float* __restrict__ x,
                             const float* __restrict__ alpha_p,
                             const float* __restrict__ ln1g, const float* __restrict__ ln1b,
                             const float* __restrict__ ln2g, const float* __restrict__ ln2b,
                             unsigned short* __restrict__ lnadj,
                             unsigned short* __restrict__ lnfeats)
{
  __shared__ __align__(16) unsigned short adjb[128 * AP];
  __shared__ __align__(16) unsigned short Pms[64 * AP];
  __shared__ __align__(16) unsigned short Z1T[64 * AP];
  __shared__ __align__(16) unsigned short xfT[16 * AP];
  __shared__ float red[16];

  const int tid = threadIdx.x;
  const int b = blockIdx.x;
  const int w = tid >> 6;
  const int lane = tid & 63;
  const int l15 = lane & 15;
  const int q = lane >> 4;
  const float a = 1.0f / (1.0f + __expf(-alpha_p[0]));
  const float na = 1.0f - a;

  {
    const float4* src = reinterpret_cast<const float4*>(adj + (size_t)b * (NN * NN));
    for (int i = tid; i < 128 * 32; i += 256) {
      int row = i >> 5, c4 = i & 31;
      float4 v = src[i];
      u32 w0 = (u32)f2bf(v.x) | ((u32)f2bf(v.y) << 16);
      u32 w1 = (u32)f2bf(v.z) | ((u32)f2bf(v.w) << 16);
      *reinterpret_cast<uint2*>(&adjb[row * AP + c4 * 4]) = make_uint2(w0, w1);
    }
  }
  {
    const uint4* Ps4 = reinterpret_cast<const uint4*>(Pbuf + (size_t)b * (MM * NN));
    const uint4* Pf4 = reinterpret_cast<const uint4*>(Pbuf + ((size_t)B_ + b) * (MM * NN));
    for (int i = tid; i < 64 * 16; i += 256) {
      int row = i >> 4, g = i & 15;
      uint4 sa = Ps4[i];
      uint4 fa = Pf4[i];
      uint4 o;
      o.x = comb2(sa.x, fa.x, a, na); o.y = comb2(sa.y, fa.y, a, na);
      o.z = comb2(sa.z, fa.z, a, na); o.w = comb2(sa.w, fa.w, a, na);
      *reinterpret_cast<uint4*>(&Pms[row * AP + g * 8]) = o;
    }
  }
  for (int i = tid; i < 2048; i += 256) {
    int n = i & 127, f = i >> 7;
    xfT[f * AP + n] = f2bf(x[((size_t)b * NN + n) * IND + 2 + f]);
  }
  __syncthreads();

  {
    f32x4 acc[2][4];
    #pragma unroll
    for (int i = 0; i < 2; ++i)
      #pragma unroll
      for (int j = 0; j < 4; ++j) acc[i][j] = f32x4{0.f, 0.f, 0.f, 0.f};
    #pragma unroll
    for (int kt = 0; kt < 4; ++kt) {
      const int d0 = 32 * kt + 8 * q;
      bf16x8 bf[4];
      #pragma unroll
      for (int j = 0; j < 4; ++j)
        bf[j] = ldfrag(&Pms[(16 * j + l15) * AP + d0]);
      #pragma unroll
      for (int ai = 0; ai < 2; ++ai) {
        bf16x8 af = ldfrag(&adjb[(32 * w + 16 * ai + l15) * AP + d0]);
        #pragma unroll
        for (int j = 0; j < 4; ++j)
          acc[ai][j] = __builtin_amdgcn_mfma_f32_16x16x32_bf16(af, bf[j], acc[ai][j], 0, 0, 0);
      }
    }
    #pragma unroll
    for (int ai = 0; ai < 2; ++ai) {
      #pragma unroll
      for (int j = 0; j < 4; ++j) {
        const int k = 16 * j + l15;
        const int nbase = 32 * w + 16 * ai + 4 * q;
        u32 w0 = (u32)f2bf(acc[ai][j][0]) | ((u32)f2bf(acc[ai][j][1]) << 16);
        u32 w1 = (u32)f2bf(acc[ai][j][2]) | ((u32)f2bf(acc[ai][j][3]) << 16);
        *reinterpret_cast<uint2*>(&Z1T[k * AP + nbase]) = make_uint2(w0, w1);
      }
    }
  }
  __syncthreads();

  f32x4 acc2[4];
  f32x4 acc3 = f32x4{0.f, 0.f, 0.f, 0.f};
  #pragma unroll
  for (int j = 0; j < 4; ++j) acc2[j] = f32x4{0.f, 0.f, 0.f, 0.f};
  #pragma unroll
  for (int nt = 0; nt < 4; ++nt) {
    const int n0 = 32 * nt + 8 * q;
    bf16x8 af = ldfrag(&Pms[(16 * w + l15) * AP + n0]);
    #pragma unroll
    for (int j = 0; j < 4; ++j) {
      bf16x8 bv = ldfrag(&Z1T[(16 * j + l15) * AP + n0]);
      acc2[j] = __builtin_amdgcn_mfma_f32_16x16x32_bf16(af, bv, acc2[j], 0, 0, 0);
    }
    bf16x8 bx = ldfrag(&xfT[l15 * AP + n0]);
    acc3 = __builtin_amdgcn_mfma_f32_16x16x32_bf16(af, bx, acc3, 0, 0, 0);
  }

  {
    float s1 = 0.f, q1 = 0.f, s2 = 0.f, q2 = 0.f;
    #pragma unroll
    for (int j = 0; j < 4; ++j)
      #pragma unroll
      for (int r = 0; r < 4; ++r) { float v = acc2[j][r]; s1 += v; q1 += v * v; }
    #pragma unroll
    for (int r = 0; r < 4; ++r) { float v = acc3[r]; s2 += v; q2 += v * v; }
    #pragma unroll
    for (int off = 1; off < 64; off <<= 1) {
      s1 += __shfl_xor(s1, off); q1 += __shfl_xor(q1, off);
      s2 += __shfl_xor(s2, off); q2 += __shfl_xor(q2, off);
    }
    if (lane == 0) { red[w] = s1; red[4 + w] = q1; red[8 + w] = s2; red[12 + w] = q2; }
  }
  __syncthreads();
  const float S1 = red[0] + red[1] + red[2] + red[3];
  const float Q1 = red[4] + red[5] + red[6] + red[7];
  const float S2 = red[8] + red[9] + red[10] + red[11];
  const float Q2 = red[12] + red[13] + red[14] + red[15];
  const float mean1 = S1 * (1.0f / 4096.0f);
  const float rstd1 = rsqrtf(Q1 * (1.0f / 4096.0f) - mean1 * mean1 + 1e-5f);
  const float mean2 = S2 * (1.0f / 1024.0f);
  const float rstd2 = rsqrtf(Q2 * (1.0f / 1024.0f) - mean2 * mean2 + 1e-5f);

  unsigned short* ob1 = adjb;
  unsigned short* ob2 = Z1T;
  #pragma unroll
  for (int j = 0; j < 4; ++j) {
    const int k = 16 * j + l15;
    #pragma unroll
    for (int r = 0; r < 4; ++r) {
      const int m = 16 * w + 4 * q + r;
      const int pos = m * 64 + k;
      float vv = (acc2[j][r] - mean1) * rstd1 * ln1g[pos] + ln1b[pos];
      ob1[pos] = f2bf(vv);
    }
  }
  {
    const int f = l15;
    #pragma unroll
    for (int r = 0; r < 4; ++r) {
      const int m = 16 * w + 4 * q + r;
      const int pos = m * 16 + f;
      float vv = (acc3[r] - mean2) * rstd2 * ln2g[pos] + ln2b[pos];
      ob2[pos] = f2bf(vv);
    }
  }
  __syncthreads();
  {
    const uint4* sp = reinterpret_cast<const uint4*>(ob1);
    uint4* dp = reinterpret_cast<uint4*>(lnadj + (size_t)b * 4096);
    for (int i = tid; i < 512; i += 256) dp[i] = sp[i];
    if (tid < 128)
      reinterpret_cast<uint4*>(lnfeats + (size_t)b * 1024)[tid] =
          reinterpret_cast<const uint4*>(ob2)[tid];
  }
}

// ---------------------------------------------------------------------------
// Kernel C (NEW, MFMA): C[M][ldc]+coff = relu(A_bf16[M][K] @ W_f32[N][K]^T + b).
// Tile 64x64, block 256 (4 waves; wave w = row-group), K-chunk 64.
// Pitch 72 u16 = ideal 8-access/bank b128 frag reads, 16B-aligned rows.
// ---------------------------------------------------------------------------
#define GP 72
__launch_bounds__(256, 2)
__global__ void gemm_mfma_kernel(const unsigned short* __restrict__ A,
                                 const float* __restrict__ W,
                                 const float* __restrict__ bias,
                                 float* __restrict__ C,
                                 int K, int ldc, int coff)
{
  __shared__ __align__(16) unsigned short At[64 * GP];
  __shared__ __align__(16) unsigned short Wt[64 * GP];
  const int tid = threadIdx.x;
  const int m0 = blockIdx.x * 64;
  const int n0 = blockIdx.y * 64;
  const int w = tid >> 6, lane = tid & 63;
  const int l15 = lane & 15, q = lane >> 4;
  const int srow = tid >> 2, sko = (tid & 3) * 16;

  f32x4 acc[4];
  #pragma unroll
  for (int j = 0; j < 4; ++j) acc[j] = f32x4{0.f, 0.f, 0.f, 0.f};

  for (int kc = 0; kc < K; kc += 64) {
    __syncthreads();
    {
      const unsigned short* ap = &A[(size_t)(m0 + srow) * K + kc + sko];
      *reinterpret_cast<uint4*>(&At[srow * GP + sko]) =
          *reinterpret_cast<const uint4*>(ap);
      *reinterpret_cast<uint4*>(&At[srow * GP + sko + 8]) =
          *reinterpret_cast<const uint4*>(ap + 8);
      const float* wp = &W[(size_t)(n0 + srow) * K + kc + sko];
      const float4 v0 = reinterpret_cast<const float4*>(wp)[0];
      const float4 v1 = reinterpret_cast<const float4*>(wp)[1];
      const float4 v2 = reinterpret_cast<const float4*>(wp)[2];
      const float4 v3 = reinterpret_cast<const float4*>(wp)[3];
      uint4 o0, o1;
      o0.x = (u32)f2bf(v0.x) | ((u32)f2bf(v0.y) << 16);
      o0.y = (u32)f2bf(v0.z) | ((u32)f2bf(v0.w) << 16);
      o0.z = (u32)f2bf(v1.x) | ((u32)f2bf(v1.y) << 16);
      o0.w = (u32)f2bf(v1.z) | ((u32)f2bf(v1.w) << 16);
      o1.x = (u32)f2bf(v2.x) | ((u32)f2bf(v2.y) << 16);
      o1.y = (u32)f2bf(v2.z) | ((u32)f2bf(v2.w) << 16);
      o1.z = (u32)f2bf(v3.x) | ((u32)f2bf(v3.y) << 16);
      o1.w = (u32)f2bf(v3.z) | ((u32)f2bf(v3.w) << 16);
      *reinterpret_cast<uint4*>(&Wt[srow * GP + sko]) = o0;
      *reinterpret_cast<uint4*>(&Wt[srow * GP + sko + 8]) = o1;
    }
    __syncthreads();
    #pragma unroll
    for (int s = 0; s < 2; ++s) {
      bf16x8 af = ldfrag(&At[(16 * w + l15) * GP + 32 * s + 8 * q]);
      #pragma unroll
      for (int j = 0; j < 4; ++j) {
        bf16x8 bf = ldfrag(&Wt[(16 * j + l15) * GP + 32 * s + 8 * q]);
        acc[j] = __builtin_amdgcn_mfma_f32_16x16x32_bf16(af, bf, acc[j], 0, 0, 0);
      }
    }
  }
  #pragma unroll
  for (int j = 0; j < 4; ++j) {
    const int col = n0 + 16 * j + l15;
    const float bb = bias[col];
    #pragma unroll
    for (int r = 0; r < 4; ++r) {
      const int m = m0 + 16 * w + 4 * q + r;
      C[(size_t)m * ldc + coff + col] = fmaxf(acc[j][r] + bb, 0.0f);
    }
  }
}

// ---------------------------------------------------------------------------
// Kernel D (NEW): 8 rows/block, grid 256. fc6(relu) -> fc7 -> log_softmax.
// ---------------------------------------------------------------------------
__launch_bounds__(256)
__global__ void head_kernel(const float* __restrict__ h45,
                            const float* __restrict__ wT6,   // [512][64]
                            const float* __restrict__ b6,
                            const float* __restrict__ w7,    // [10][64]
                            const float* __restrict__ b7,
                            float* __restrict__ out)
{
  __shared__ float row[8][512];
  __shared__ float h6[8][64];
  __shared__ float zb[8][12];
  const int tid = threadIdx.x;
  const int r0 = blockIdx.x * 8;
  for (int i = tid; i < 8 * 128; i += 256) {
    int r = i >> 7, c4 = i & 127;
    *reinterpret_cast<float4*>(&row[r][c4 * 4]) =
        reinterpret_cast<const float4*>(h45 + (size_t)(r0 + r) * 512)[c4];
  }
  __syncthreads();
  const int o = tid & 63, rg = tid >> 6;
  float a0 = b6[o], a1 = a0;
  #pragma unroll 8
  for (int k = 0; k < 512; ++k) {
    float wv = wT6[k * 64 + o];
    a0 += row[rg][k] * wv;
    a1 += row[rg + 4][k] * wv;
  }
  h6[rg][o] = fmaxf(a0, 0.0f);
  h6[rg + 4][o] = fmaxf(a1, 0.0f);
  __syncthreads();
  if (tid < 80) {
    int r = tid / 10, c = tid - r * 10;
    float z = b7[c];
    #pragma unroll
    for (int k = 0; k < 64; ++k) z += h6[r][k] * w7[c * 64 + k];
    zb[r][c] = z;
  }
  __syncthreads();
  if (tid < 80) {
    int r = tid / 10, c = tid - r * 10;
    float mx = zb[r][0];
    #pragma unroll
    for (int j = 1; j < 10; ++j) mx = fmaxf(mx, zb[r][j]);
    float se = 0.f;
    #pragma unroll
    for (int j = 0; j < 10; ++j) se += __expf(zb[r][j] - mx);
    out[(size_t)(r0 + r) * 10 + c] = zb[r][c] - mx - __logf(se);
  }
}

__global__ void transpose_kernel(const float* __restrict__ in, float* __restrict__ outp,
                                 int R, int Cc)
{
  int idx = blockIdx.x * blockDim.x + threadIdx.x;
  int total = R * Cc;
  for (; idx < total; idx += gridDim.x * blockDim.x) {
    int rr = idx / Cc, cc = idx - rr * Cc;
    outp[cc * R + rr] = in[idx];
  }
}

// ---------------------------------------------------------------------------
extern "C" void kernel_launch(void* const* d_in, const int* in_sizes, int n_in,
                              void* d_out, int out_size, void* d_ws, size_t ws_size,
                              hipStream_t stream)
{
  (void)in_sizes; (void)n_in; (void)out_size; (void)ws_size;
  const float* x    = (const float*)d_in[0];
  const float* adj  = (const float*)d_in[1];
  const float* w1   = (const float*)d_in[2];
  const float* w2   = (const float*)d_in[3];
  const float* alpha = (const float*)d_in[4];
  const float* bin_score = (const float*)d_in[5];
  const float* fc2w = (const float*)d_in[6];
  const float* fc2b = (const float*)d_in[7];
  const float* fc3w = (const float*)d_in[8];
  const float* fc3b = (const float*)d_in[9];
  const float* ln1g = (const float*)d_in[10];
  const float* ln1b = (const float*)d_in[11];
  const float* fc4w = (const float*)d_in[12];
  const float* fc4b = (const float*)d_in[13];
  const float* ln2g = (const float*)d_in[14];
  const float* ln2b = (const float*)d_in[15];
  const float* fc5w = (const float*)d_in[16];
  const float* fc5b = (const float*)d_in[17];
  const float* fc6w = (const float*)d_in[18];
  const float* fc6b = (const float*)d_in[19];
  const float* fc7w = (const float*)d_in[20];
  const float* fc7b = (const float*)d_in[21];
  float* out = (float*)d_out;

  char* ws = (char*)d_ws;
  unsigned short* Pbuf = (unsigned short*)ws;                       // 4096*8192 bf16 = 64 MB
  size_t off = (size_t)4096 * 8192 * 2;
  unsigned short* lnadj = (unsigned short*)(ws + off);  off += (size_t)2048 * 4096 * 2;
  unsigned short* lnfeats = (unsigned short*)(ws + off); off += (size_t)2048 * 1024 * 2;
  float* h45 = (float*)(ws + off);                      off += (size_t)2048 * 512 * 4;
  float* wT6 = (float*)(ws + off);                      off += (size_t)512 * 64 * 4;

  hipLaunchKernelGGL(ot_kernel, dim3(2048, 2), dim3(64), 0, stream,
                     x, w1, w2, fc2w, fc2b, fc3w, fc3b, bin_score, Pbuf);
  hipLaunchKernelGGL(transpose_kernel, dim3(32), dim3(256), 0, stream, fc6w, wT6, 64, 512);
  hipLaunchKernelGGL(align_kernel, dim3(2048), dim3(256), 0, stream,
                     Pbuf, adj, x, alpha, ln1g, ln1b, ln2g, ln2b, lnadj, lnfeats);
  hipLaunchKernelGGL(gemm_mfma_kernel, dim3(32, 4), dim3(256), 0, stream,
                     lnadj, fc4w, fc4b, h45, 4096, 512, 0);
  hipLaunchKernelGGL(gemm_mfma_kernel, dim3(32, 4), dim3(256), 0, stream,
                     lnfeats, fc5w, fc5b, h45, 1024, 512, 256);
  hipLaunchKernelGGL(head_kernel, dim3(256), dim3(256), 0, stream,
                     h45, wT6, fc6b, fc7w, fc7b, out);
}

// Round 6
// 242.446 us; speedup vs baseline: 3.4093x; 1.2953x over previous
//
#include <hip/hip_runtime.h>
#include <hip/hip_bf16.h>
#include <hip/hip_fp16.h>

// Problem constants
#define B_   2048
#define NN   128    // NMAX
#define MM   64     // HN
#define HD_  128
#define IND  18
#define FD_  16

typedef unsigned int u32;
typedef _Float16 h2_t __attribute__((ext_vector_type(2)));
typedef __attribute__((ext_vector_type(8))) short bf16x8;
typedef __attribute__((ext_vector_type(4))) float f32x4;

__device__ __forceinline__ float fdot2f(u32 a, u32 b, float c) {
#if defined(__has_builtin)
#if __has_builtin(__builtin_amdgcn_fdot2)
  return __builtin_amdgcn_fdot2(__builtin_bit_cast(h2_t, a),
                                __builtin_bit_cast(h2_t, b), c, false);
#else
  h2_t x = __builtin_bit_cast(h2_t, a), y = __builtin_bit_cast(h2_t, b);
  return c + (float)x[0] * (float)y[0] + (float)x[1] * (float)y[1];
#endif
#else
  h2_t x = __builtin_bit_cast(h2_t, a), y = __builtin_bit_cast(h2_t, b);
  return c + (float)x[0] * (float)y[0] + (float)x[1] * (float)y[1];
#endif
}

__device__ __forceinline__ u32 pk2(float a, float b) {
#if defined(__has_builtin)
#if __has_builtin(__builtin_amdgcn_cvt_pkrtz)
  return __builtin_bit_cast(u32, __builtin_amdgcn_cvt_pkrtz(a, b));
#else
  __half ha = __float2half_rn(a), hb = __float2half_rn(b);
  return (u32)__half_as_ushort(ha) | ((u32)__half_as_ushort(hb) << 16);
#endif
#else
  __half ha = __float2half_rn(a), hb = __float2half_rn(b);
  return (u32)__half_as_ushort(ha) | ((u32)__half_as_ushort(hb) << 16);
#endif
}

__device__ __forceinline__ float rcpf_(float x) {
#if defined(__has_builtin)
#if __has_builtin(__builtin_amdgcn_rcpf)
  return __builtin_amdgcn_rcpf(x);
#else
  return 1.0f / x;
#endif
#else
  return 1.0f / x;
#endif
}

__device__ __forceinline__ float h_lo(u32 d) {
  return __half2float(__ushort_as_half((unsigned short)(d & 0xffffu)));
}
__device__ __forceinline__ float h_hi(u32 d) {
  return __half2float(__ushort_as_half((unsigned short)(d >> 16)));
}

__device__ __forceinline__ float bf2f(unsigned short u) {
  union { float f; u32 i; } z; z.i = ((u32)u) << 16; return z.f;
}
__device__ __forceinline__ unsigned short f2bf(float f) {
  union { float fv; u32 u; } z; z.fv = f;
  u32 lsb = (z.u >> 16) & 1u;
  return (unsigned short)((z.u + 0x7fffu + lsb) >> 16);
}
__device__ __forceinline__ u32 bfpk(float a, float b) {
  return (u32)f2bf(a) | ((u32)f2bf(b) << 16);
}

// ---------------------------------------------------------------------------
// Kernel A: ONE WAVE per (batch, stream) OT problem. grid (2048,2), block 64.
// Phase 1 rewritten on bf16 MFMA:
//   act  = relu(x_slice[16xK32] @ fcw[128ch x K32]^T + b)   (8 MFMAs/slice)
//   (LDS transpose bounce, 16x128 bf16)
//   K    = f16(min(exp(relu(w[64x128] @ act_slice^T)), 6e4)) (16 MFMAs/slice)
// A-frag: lane&15 = row, lane>>4 = k-octet. B-frag: lane&15 = col, same k.
// D: col = lane&15, row = 4*(lane>>4)+reg   [verified layout, align_kernel].
// Sinkhorn unchanged (exp-space, register K); TOL 3e-4, every-iter __all exit.
// ---------------------------------------------------------------------------
__launch_bounds__(64, 2)
__global__ void ot_kernel(const float* __restrict__ x,
                          const float* __restrict__ w1,
                          const float* __restrict__ w2,
                          const float* __restrict__ fc2w, const float* __restrict__ fc2b,
                          const float* __restrict__ fc3w, const float* __restrict__ fc3b,
                          const float* __restrict__ bin_score,
                          unsigned short* __restrict__ Pbuf)
{
  __shared__ __align__(16) u32 Ksh[64 * 68];              // K f16, pitch 68 dw (136 h)
  __shared__ __align__(16) unsigned short actL[16 * 136]; // act slice bf16
  __shared__ __align__(16) u32 vhs[64];                   // v packed f16 pairs
  __shared__ __align__(16) u32 uhs[32];                   // u packed f16 pairs

  const int l = threadIdx.x;
  const int b = blockIdx.x, s = blockIdx.y;
  const int l15 = l & 15, q = l >> 4;
  const float* wm = s ? w2 : w1;
  const float* fw = s ? fc3w : fc2w;
  const float* fb = s ? fc3b : fc2b;
  unsigned short* Kshh = reinterpret_cast<unsigned short*>(Ksh);

  // ---- preload w A-frags (rows m = 16at+l15, ch-octet q within kt) ----
  uint4 wA[4][4];
  #pragma unroll
  for (int at = 0; at < 4; ++at) {
    const float* wrow = wm + (size_t)(16 * at + l15) * 128;
    #pragma unroll
    for (int kt = 0; kt < 4; ++kt) {
      float4 va = *reinterpret_cast<const float4*>(wrow + 32 * kt + 8 * q);
      float4 vb = *reinterpret_cast<const float4*>(wrow + 32 * kt + 8 * q + 4);
      wA[at][kt] = make_uint4(bfpk(va.x, va.y), bfpk(va.z, va.w),
                              bfpk(vb.x, vb.y), bfpk(vb.z, vb.w));
    }
  }
  // ---- preload fcw B-frags (col ch = 16nt+l15, ind-octet q, K=32 zero-pad) ----
  uint4 fcwB[8];
  #pragma unroll
  for (int nt = 0; nt < 8; ++nt) {
    const int ch = 16 * nt + l15;
    uint4 o = make_uint4(0u, 0u, 0u, 0u);
    if (s) {
      if (q < 2) {
        const float* fr = fw + (size_t)ch * 16 + 8 * q;
        float4 va = *reinterpret_cast<const float4*>(fr);
        float4 vb = *reinterpret_cast<const float4*>(fr + 4);
        o = make_uint4(bfpk(va.x, va.y), bfpk(va.z, va.w),
                       bfpk(vb.x, vb.y), bfpk(vb.z, vb.w));
      }
    } else {
      if (q == 0) o.x = bfpk(fw[ch * 2], fw[ch * 2 + 1]);
    }
    fcwB[nt] = o;
  }
  float bb[8];
  #pragma unroll
  for (int nt = 0; nt < 8; ++nt) bb[nt] = fb[16 * nt + l15];

  // ---- preload x A-frags (row node = 16mt+l15, ind-octet q; float2 loads: 8B-aligned) ----
  uint4 xa[8];
  #pragma unroll
  for (int mt = 0; mt < 8; ++mt) {
    const int node = 16 * mt + l15;
    const float* xp = x + ((size_t)b * NN + node) * IND + (s ? 2 : 0);
    uint4 o = make_uint4(0u, 0u, 0u, 0u);
    if (s) {
      if (q < 2) {
        float2 p0 = *reinterpret_cast<const float2*>(xp + 8 * q);
        float2 p1 = *reinterpret_cast<const float2*>(xp + 8 * q + 2);
        float2 p2 = *reinterpret_cast<const float2*>(xp + 8 * q + 4);
        float2 p3 = *reinterpret_cast<const float2*>(xp + 8 * q + 6);
        o = make_uint4(bfpk(p0.x, p0.y), bfpk(p1.x, p1.y),
                       bfpk(p2.x, p2.y), bfpk(p3.x, p3.y));
      }
    } else {
      if (q == 0) {
        float2 p0 = *reinterpret_cast<const float2*>(xp);
        o.x = bfpk(p0.x, p0.y);
      }
    }
    xa[mt] = o;
  }
  const float ebs = __expf(bin_score[0]);

  // ---- Phase 1: 8 slices of 16 nodes ----
  #pragma unroll
  for (int mt = 0; mt < 8; ++mt) {
    f32x4 acc[8];
    #pragma unroll
    for (int nt = 0; nt < 8; ++nt)
      acc[nt] = __builtin_amdgcn_mfma_f32_16x16x32_bf16(
          __builtin_bit_cast(bf16x8, xa[mt]), __builtin_bit_cast(bf16x8, fcwB[nt]),
          f32x4{0.f, 0.f, 0.f, 0.f}, 0, 0, 0);
    // bias+relu -> bf16, transpose-bounce: actL[node-local 4q+r][ch 16nt+l15]
    #pragma unroll
    for (int nt = 0; nt < 8; ++nt) {
      #pragma unroll
      for (int r = 0; r < 4; ++r) {
        float v = fmaxf(acc[nt][r] + bb[nt], 0.0f);
        actL[(4 * q + r) * 136 + 16 * nt + l15] = f2bf(v);
      }
    }
    // scores B-frags: act[node=l15][ch = 32kt+8q+j]
    uint4 sB[4];
    #pragma unroll
    for (int kt = 0; kt < 4; ++kt)
      sB[kt] = *reinterpret_cast<const uint4*>(&actL[l15 * 136 + 32 * kt + 8 * q]);
    #pragma unroll
    for (int at = 0; at < 4; ++at) {
      f32x4 sa = f32x4{0.f, 0.f, 0.f, 0.f};
      #pragma unroll
      for (int kt = 0; kt < 4; ++kt)
        sa = __builtin_amdgcn_mfma_f32_16x16x32_bf16(
            __builtin_bit_cast(bf16x8, wA[at][kt]), __builtin_bit_cast(bf16x8, sB[kt]),
            sa, 0, 0, 0);
      // K[m = 16at+4q+r][node = 16mt+l15] = f16(min(exp(relu(s)), 6e4))
      #pragma unroll
      for (int r = 0; r < 4; ++r) {
        float kv = fminf(__expf(fmaxf(sa[r], 0.0f)), 60000.0f);
        Kshh[(16 * at + 4 * q + r) * 136 + 16 * mt + l15] =
            __half_as_ushort(__float2half_rn(kv));
      }
    }
  }

  // ---- register K tiles (unchanged) ----
  u32 kr[64];
  #pragma unroll
  for (int t = 0; t < 16; ++t) {
    uint4 kv = *reinterpret_cast<const uint4*>(Ksh + l * 68 + 4 * t);
    kr[4 * t + 0] = kv.x; kr[4 * t + 1] = kv.y;
    kr[4 * t + 2] = kv.z; kr[4 * t + 3] = kv.w;
  }
  u32 kta[32], ktb[32];
  #pragma unroll
  for (int j = 0; j < 32; ++j) {
    u32 d0 = Ksh[(2 * j) * 68 + l];
    u32 d1 = Ksh[(2 * j + 1) * 68 + l];
    kta[j] = (d0 & 0xffffu) | (d1 << 16);
    ktb[j] = (d0 >> 16) | (d1 & 0xffff0000u);
  }

  // ---- Phase 2: barrier-free exp-space Sinkhorn ----
  vhs[l] = 0x3C003C00u;
  float v128 = 1.0f, sum_v = 129.0f;
  float u_old = 0.0f, vo0 = 1.0f, vo1 = 1.0f;
  float ur = 0.0f;
  const float TOL = 3e-4f;

  for (int it = 0; it < 100; ++it) {
    const float u64v = 128.0f * rcpf_(ebs * sum_v);
    float a0 = ebs * v128, a1 = 0.f, a2 = 0.f, a3 = 0.f;
    const uint4* vh4 = reinterpret_cast<const uint4*>(vhs);
    #pragma unroll
    for (int t = 0; t < 16; ++t) {
      uint4 vv = vh4[t];
      a0 = fdot2f(kr[4 * t + 0], vv.x, a0);
      a1 = fdot2f(kr[4 * t + 1], vv.y, a1);
      a2 = fdot2f(kr[4 * t + 2], vv.z, a2);
      a3 = fdot2f(kr[4 * t + 3], vv.w, a3);
    }
    float urn = rcpf_((a0 + a1) + (a2 + a3));
    float m1 = fabsf(urn - u_old) - TOL * urn;
    u_old = urn; ur = urn;
    float su = urn;
    su += __shfl_xor(su, 1);  su += __shfl_xor(su, 2);
    su += __shfl_xor(su, 4);  su += __shfl_xor(su, 8);
    su += __shfl_xor(su, 16); su += __shfl_xor(su, 32);
    const float sum_u = su + u64v;
    const float v128n = 64.0f * rcpf_(ebs * sum_u);
    float upr = __shfl_xor(urn, 1);
    if (!(l & 1)) uhs[l >> 1] = pk2(urn, upr);
    float c0a = ebs * u64v, c0b = 0.f, c1a = ebs * u64v, c1b = 0.f;
    const uint4* uh4 = reinterpret_cast<const uint4*>(uhs);
    #pragma unroll
    for (int t = 0; t < 8; ++t) {
      uint4 uu = uh4[t];
      c0a = fdot2f(kta[4 * t + 0], uu.x, c0a);
      c0b = fdot2f(kta[4 * t + 1], uu.y, c0b);
      c0a = fdot2f(kta[4 * t + 2], uu.z, c0a);
      c0b = fdot2f(kta[4 * t + 3], uu.w, c0b);
      c1a = fdot2f(ktb[4 * t + 0], uu.x, c1a);
      c1b = fdot2f(ktb[4 * t + 1], uu.y, c1b);
      c1a = fdot2f(ktb[4 * t + 2], uu.z, c1a);
      c1b = fdot2f(ktb[4 * t + 3], uu.w, c1b);
    }
    float v0n = rcpf_(c0a + c0b);
    float v1n = rcpf_(c1a + c1b);
    float m2 = fabsf(v0n - vo0) - TOL * v0n;
    float m3 = fabsf(v1n - vo1) - TOL * v1n;
    vo0 = v0n; vo1 = v1n;
    vhs[l] = pk2(v0n, v1n);
    float sv = v0n + v1n;
    sv += __shfl_xor(sv, 1);  sv += __shfl_xor(sv, 2);
    sv += __shfl_xor(sv, 4);  sv += __shfl_xor(sv, 8);
    sv += __shfl_xor(sv, 16); sv += __shfl_xor(sv, 32);
    sum_v = sv + v128n;
    v128 = v128n;
    float mcond = fmaxf(m1, fmaxf(m2, m3));
    if (__all(mcond <= 0.0f)) break;
  }

  // ---- Phase 3: P[l][n] = K*u*v -> bf16 ----
  {
    unsigned short* Pout = Pbuf + ((size_t)(s * B_ + b)) * (MM * NN);
    uint4* P4 = reinterpret_cast<uint4*>(Pout);
    const uint4* vh4 = reinterpret_cast<const uint4*>(vhs);
    #pragma unroll
    for (int t = 0; t < 16; ++t) {
      uint4 vv = vh4[t];
      u32 o0, o1, o2, o3;
#define PDW(KD, VD, OUT) do {                                                 \
      float p0 = h_lo(KD) * ur * h_lo(VD);                                    \
      float p1 = h_hi(KD) * ur * h_hi(VD);                                    \
      OUT = (u32)f2bf(p0) | ((u32)f2bf(p1) << 16);                            \
    } while (0)
      PDW(kr[4 * t + 0], vv.x, o0);
      PDW(kr[4 * t + 1], vv.y, o1);
      PDW(kr[4 * t + 2], vv.z, o2);
      PDW(kr[4 * t + 3], vv.w, o3);
#undef PDW
      P4[l * 16 + t] = make_uint4(o0, o1, o2, o3);
    }
  }
}

// ---------------------------------------------------------------------------
// Kernel B (MFMA): unchanged (passed, ~47us).
// ---------------------------------------------------------------------------
#define AP 136   // bf16 row pitch (272 B, 16B aligned)

__device__ __forceinline__ bf16x8 ldfrag(const unsigned short* p) {
  return __builtin_bit_cast(bf16x8, *reinterpret_cast<const uint4*>(p));
}
__device__ __forceinline__ u32 comb2(u32 ps, u32 pf, float a, float na) {
  float r0 = a * bf2f((unsigned short)(ps & 0xffffu)) + na * bf2f((unsigned short)(pf & 0xffffu));
  float r1 = a * bf2f((unsigned short)(ps >> 16)) + na * bf2f((unsigned short)(pf >> 16));
  return (u32)f2bf(r0) | ((u32)f2bf(r1) << 16);
}

__launch_bounds__(256, 2)
__global__ void align_kernel(const unsigned short* __restrict__ Pbuf,
                             const float* __restrict__ adj,
                             const float* __restrict__ x,
                             const float* __restrict__ alpha_p,
                             const float* __restrict__ ln1g, const float* __restrict__ ln1b,
                             const float* __restrict__ ln2g, const float* __restrict__ ln2b,
                             unsigned short* __restrict__ lnadj,
                             unsigned short* __restrict__ lnfeats)
{
  __shared__ __align__(16) unsigned short adjb[128 * AP];
  __shared__ __align__(16) unsigned short Pms[64 * AP];
  __shared__ __align__(16) unsigned short Z1T[64 * AP];
  __shared__ __align__(16) unsigned short xfT[16 * AP];
  __shared__ float red[16];

  const int tid = threadIdx.x;
  const int b = blockIdx.x;
  const int w = tid >> 6;
  const int lane = tid & 63;
  const int l15 = lane & 15;
  const int q = lane >> 4;
  const float a = 1.0f / (1.0f + __expf(-alpha_p[0]));
  const float na = 1.0f - a;

  {
    const float4* src = reinterpret_cast<const float4*>(adj + (size_t)b * (NN * NN));
    for (int i = tid; i < 128 * 32; i += 256) {
      int row = i >> 5, c4 = i & 31;
      float4 v = src[i];
      u32 w0 = (u32)f2bf(v.x) | ((u32)f2bf(v.y) << 16);
      u32 w1 = (u32)f2bf(v.z) | ((u32)f2bf(v.w) << 16);
      *reinterpret_cast<uint2*>(&adjb[row * AP + c4 * 4]) = make_uint2(w0, w1);
    }
  }
  {
    const uint4* Ps4 = reinterpret_cast<const uint4*>(Pbuf + (size_t)b * (MM * NN));
    const uint4* Pf4 = reinterpret_cast<const uint4*>(Pbuf + ((size_t)B_ + b) * (MM * NN));
    for (int i = tid; i < 64 * 16; i += 256) {
      int row = i >> 4, g = i & 15;
      uint4 sa = Ps4[i];
      uint4 fa = Pf4[i];
      uint4 o;
      o.x = comb2(sa.x, fa.x, a, na); o.y = comb2(sa.y, fa.y, a, na);
      o.z = comb2(sa.z, fa.z, a, na); o.w = comb2(sa.w, fa.w, a, na);
      *reinterpret_cast<uint4*>(&Pms[row * AP + g * 8]) = o;
    }
  }
  for (int i = tid; i < 2048; i += 256) {
    int n = i & 127, f = i >> 7;
    xfT[f * AP + n] = f2bf(x[((size_t)b * NN + n) * IND + 2 + f]);
  }
  __syncthreads();

  {
    f32x4 acc[2][4];
    #pragma unroll
    for (int i = 0; i < 2; ++i)
      #pragma unroll
      for (int j = 0; j < 4; ++j) acc[i][j] = f32x4{0.f, 0.f, 0.f, 0.f};
    #pragma unroll
    for (int kt = 0; kt < 4; ++kt) {
      const int d0 = 32 * kt + 8 * q;
      bf16x8 bf[4];
      #pragma unroll
      for (int j = 0; j < 4; ++j)
        bf[j] = ldfrag(&Pms[(16 * j + l15) * AP + d0]);
      #pragma unroll
      for (int ai = 0; ai < 2; ++ai) {
        bf16x8 af = ldfrag(&adjb[(32 * w + 16 * ai + l15) * AP + d0]);
        #pragma unroll
        for (int j = 0; j < 4; ++j)
          acc[ai][j] = __builtin_amdgcn_mfma_f32_16x16x32_bf16(af, bf[j], acc[ai][j], 0, 0, 0);
      }
    }
    #pragma unroll
    for (int ai = 0; ai < 2; ++ai) {
      #pragma unroll
      for (int j = 0; j < 4; ++j) {
        const int k = 16 * j + l15;
        const int nbase = 32 * w + 16 * ai + 4 * q;
        u32 w0 = (u32)f2bf(acc[ai][j][0]) | ((u32)f2bf(acc[ai][j][1]) << 16);
        u32 w1 = (u32)f2bf(acc[ai][j][2]) | ((u32)f2bf(acc[ai][j][3]) << 16);
        *reinterpret_cast<uint2*>(&Z1T[k * AP + nbase]) = make_uint2(w0, w1);
      }
    }
  }
  __syncthreads();

  f32x4 acc2[4];
  f32x4 acc3 = f32x4{0.f, 0.f, 0.f, 0.f};
  #pragma unroll
  for (int j = 0; j < 4; ++j) acc2[j] = f32x4{0.f, 0.f, 0.f, 0.f};
  #pragma unroll
  for (int nt = 0; nt < 4; ++nt) {
    const int n0 = 32 * nt + 8 * q;
    bf16x8 af = ldfrag(&Pms[(16 * w + l15) * AP + n0]);
    #pragma unroll
    for (int j = 0; j < 4; ++j) {
      bf16x8 bv = ldfrag(&Z1T[(16 * j + l15) * AP + n0]);
      acc2[j] = __builtin_amdgcn_mfma_f32_16x16x32_bf16(af, bv, acc2[j], 0, 0, 0);
    }
    bf16x8 bx = ldfrag(&xfT[l15 * AP + n0]);
    acc3 = __builtin_amdgcn_mfma_f32_16x16x32_bf16(af, bx, acc3, 0, 0, 0);
  }

  {
    float s1 = 0.f, q1 = 0.f, s2 = 0.f, q2 = 0.f;
    #pragma unroll
    for (int j = 0; j < 4; ++j)
      #pragma unroll
      for (int r = 0; r < 4; ++r) { float v = acc2[j][r]; s1 += v; q1 += v * v; }
    #pragma unroll
    for (int r = 0; r < 4; ++r) { float v = acc3[r]; s2 += v; q2 += v * v; }
    #pragma unroll
    for (int off = 1; off < 64; off <<= 1) {
      s1 += __shfl_xor(s1, off); q1 += __shfl_xor(q1, off);
      s2 += __shfl_xor(s2, off); q2 += __shfl_xor(q2, off);
    }
    if (lane == 0) { red[w] = s1; red[4 + w] = q1; red[8 + w] = s2; red[12 + w] = q2; }
  }
  __syncthreads();
  const float S1 = red[0] + red[1] + red[2] + red[3];
  const float Q1 = red[4] + red[5] + red[6] + red[7];
  const float S2 = red[8] + red[9] + red[10] + red[11];
  const float Q2 = red[12] + red[13] + red[14] + red[15];
  const float mean1 = S1 * (1.0f / 4096.0f);
  const float rstd1 = rsqrtf(Q1 * (1.0f / 4096.0f) - mean1 * mean1 + 1e-5f);
  const float mean2 = S2 * (1.0f / 1024.0f);
  const float rstd2 = rsqrtf(Q2 * (1.0f / 1024.0f) - mean2 * mean2 + 1e-5f);

  unsigned short* ob1 = adjb;
  unsigned short* ob2 = Z1T;
  #pragma unroll
  for (int j = 0; j < 4; ++j) {
    const int k = 16 * j + l15;
    #pragma unroll
    for (int r = 0; r < 4; ++r) {
      const int m = 16 * w + 4 * q + r;
      const int pos = m * 64 + k;
      float vv = (acc2[j][r] - mean1) * rstd1 * ln1g[pos] + ln1b[pos];
      ob1[pos] = f2bf(vv);
    }
  }
  {
    const int f = l15;
    #pragma unroll
    for (int r = 0; r < 4; ++r) {
      const int m = 16 * w + 4 * q + r;
      const int pos = m * 16 + f;
      float vv = (acc3[r] - mean2) * rstd2 * ln2g[pos] + ln2b[pos];
      ob2[pos] = f2bf(vv);
    }
  }
  __syncthreads();
  {
    const uint4* sp = reinterpret_cast<const uint4*>(ob1);
    uint4* dp = reinterpret_cast<uint4*>(lnadj + (size_t)b * 4096);
    for (int i = tid; i < 512; i += 256) dp[i] = sp[i];
    if (tid < 128)
      reinterpret_cast<uint4*>(lnfeats + (size_t)b * 1024)[tid] =
          reinterpret_cast<const uint4*>(ob2)[tid];
  }
}

// ---------------------------------------------------------------------------
// Kernel C (MFMA): unchanged from R5.
// ---------------------------------------------------------------------------
#define GP 72
__launch_bounds__(256, 2)
__global__ void gemm_mfma_kernel(const unsigned short* __restrict__ A,
                                 const float* __restrict__ W,
                                 const float* __restrict__ bias,
                                 float* __restrict__ C,
                                 int K, int ldc, int coff)
{
  __shared__ __align__(16) unsigned short At[64 * GP];
  __shared__ __align__(16) unsigned short Wt[64 * GP];
  const int tid = threadIdx.x;
  const int m0 = blockIdx.x * 64;
  const int n0 = blockIdx.y * 64;
  const int w = tid >> 6, lane = tid & 63;
  const int l15 = lane & 15, q = lane >> 4;
  const int srow = tid >> 2, sko = (tid & 3) * 16;

  f32x4 acc[4];
  #pragma unroll
  for (int j = 0; j < 4; ++j) acc[j] = f32x4{0.f, 0.f, 0.f, 0.f};

  for (int kc = 0; kc < K; kc += 64) {
    __syncthreads();
    {
      const unsigned short* ap = &A[(size_t)(m0 + srow) * K + kc + sko];
      *reinterpret_cast<uint4*>(&At[srow * GP + sko]) =
          *reinterpret_cast<const uint4*>(ap);
      *reinterpret_cast<uint4*>(&At[srow * GP + sko + 8]) =
          *reinterpret_cast<const uint4*>(ap + 8);
      const float* wp = &W[(size_t)(n0 + srow) * K + kc + sko];
      const float4 v0 = reinterpret_cast<const float4*>(wp)[0];
      const float4 v1 = reinterpret_cast<const float4*>(wp)[1];
      const float4 v2 = reinterpret_cast<const float4*>(wp)[2];
      const float4 v3 = reinterpret_cast<const float4*>(wp)[3];
      uint4 o0, o1;
      o0.x = (u32)f2bf(v0.x) | ((u32)f2bf(v0.y) << 16);
      o0.y = (u32)f2bf(v0.z) | ((u32)f2bf(v0.w) << 16);
      o0.z = (u32)f2bf(v1.x) | ((u32)f2bf(v1.y) << 16);
      o0.w = (u32)f2bf(v1.z) | ((u32)f2bf(v1.w) << 16);
      o1.x = (u32)f2bf(v2.x) | ((u32)f2bf(v2.y) << 16);
      o1.y = (u32)f2bf(v2.z) | ((u32)f2bf(v2.w) << 16);
      o1.z = (u32)f2bf(v3.x) | ((u32)f2bf(v3.y) << 16);
      o1.w = (u32)f2bf(v3.z) | ((u32)f2bf(v3.w) << 16);
      *reinterpret_cast<uint4*>(&Wt[srow * GP + sko]) = o0;
      *reinterpret_cast<uint4*>(&Wt[srow * GP + sko + 8]) = o1;
    }
    __syncthreads();
    #pragma unroll
    for (int s = 0; s < 2; ++s) {
      bf16x8 af = ldfrag(&At[(16 * w + l15) * GP + 32 * s + 8 * q]);
      #pragma unroll
      for (int j = 0; j < 4; ++j) {
        bf16x8 bf = ldfrag(&Wt[(16 * j + l15) * GP + 32 * s + 8 * q]);
        acc[j] = __builtin_amdgcn_mfma_f32_16x16x32_bf16(af, bf, acc[j], 0, 0, 0);
      }
    }
  }
  #pragma unroll
  for (int j = 0; j < 4; ++j) {
    const int col = n0 + 16 * j + l15;
    const float bb = bias[col];
    #pragma unroll
    for (int r = 0; r < 4; ++r) {
      const int m = m0 + 16 * w + 4 * q + r;
      C[(size_t)m * ldc + coff + col] = fmaxf(acc[j][r] + bb, 0.0f);
    }
  }
}

// ---------------------------------------------------------------------------
// Kernel D: unchanged from R5 (8 rows/block).
// ---------------------------------------------------------------------------
__launch_bounds__(256)
__global__ void head_kernel(const float* __restrict__ h45,
                            const float* __restrict__ wT6,   // [512][64]
                            const float* __restrict__ b6,
                            const float* __restrict__ w7,    // [10][64]
                            const float* __restrict__ b7,
                            float* __restrict__ out)
{
  __shared__ float row[8][512];
  __shared__ float h6[8][64];
  __shared__ float zb[8][12];
  const int tid = threadIdx.x;
  const int r0 = blockIdx.x * 8;
  for (int i = tid; i < 8 * 128; i += 256) {
    int r = i >> 7, c4 = i & 127;
    *reinterpret_cast<float4*>(&row[r][c4 * 4]) =
        reinterpret_cast<const float4*>(h45 + (size_t)(r0 + r) * 512)[c4];
  }
  __syncthreads();
  const int o = tid & 63, rg = tid >> 6;
  float a0 = b6[o], a1 = a0;
  #pragma unroll 8
  for (int k = 0; k < 512; ++k) {
    float wv = wT6[k * 64 + o];
    a0 += row[rg][k] * wv;
    a1 += row[rg + 4][k] * wv;
  }
  h6[rg][o] = fmaxf(a0, 0.0f);
  h6[rg + 4][o] = fmaxf(a1, 0.0f);
  __syncthreads();
  if (tid < 80) {
    int r = tid / 10, c = tid - r * 10;
    float z = b7[c];
    #pragma unroll
    for (int k = 0; k < 64; ++k) z += h6[r][k] * w7[c * 64 + k];
    zb[r][c] = z;
  }
  __syncthreads();
  if (tid < 80) {
    int r = tid / 10, c = tid - r * 10;
    float mx = zb[r][0];
    #pragma unroll
    for (int j = 1; j < 10; ++j) mx = fmaxf(mx, zb[r][j]);
    float se = 0.f;
    #pragma unroll
    for (int j = 0; j < 10; ++j) se += __expf(zb[r][j] - mx);
    out[(size_t)(r0 + r) * 10 + c] = zb[r][c] - mx - __logf(se);
  }
}

__global__ void transpose_kernel(const float* __restrict__ in, float* __restrict__ outp,
                                 int R, int Cc)
{
  int idx = blockIdx.x * blockDim.x + threadIdx.x;
  int total = R * Cc;
  for (; idx < total; idx += gridDim.x * blockDim.x) {
    int rr = idx / Cc, cc = idx - rr * Cc;
    outp[cc * R + rr] = in[idx];
  }
}

// ---------------------------------------------------------------------------
extern "C" void kernel_launch(void* const* d_in, const int* in_sizes, int n_in,
                              void* d_out, int out_size, void* d_ws, size_t ws_size,
                              hipStream_t stream)
{
  (void)in_sizes; (void)n_in; (void)out_size; (void)ws_size;
  const float* x    = (const float*)d_in[0];
  const float* adj  = (const float*)d_in[1];
  const float* w1   = (const float*)d_in[2];
  const float* w2   = (const float*)d_in[3];
  const float* alpha = (const float*)d_in[4];
  const float* bin_score = (const float*)d_in[5];
  const float* fc2w = (const float*)d_in[6];
  const float* fc2b = (const float*)d_in[7];
  const float* fc3w = (const float*)d_in[8];
  const float* fc3b = (const float*)d_in[9];
  const float* ln1g = (const float*)d_in[10];
  const float* ln1b = (const float*)d_in[11];
  const float* fc4w = (const float*)d_in[12];
  const float* fc4b = (const float*)d_in[13];
  const float* ln2g = (const float*)d_in[14];
  const float* ln2b = (const float*)d_in[15];
  const float* fc5w = (const float*)d_in[16];
  const float* fc5b = (const float*)d_in[17];
  const float* fc6w = (const float*)d_in[18];
  const float* fc6b = (const float*)d_in[19];
  const float* fc7w = (const float*)d_in[20];
  const float* fc7b = (const float*)d_in[21];
  float* out = (float*)d_out;

  char* ws = (char*)d_ws;
  unsigned short* Pbuf = (unsigned short*)ws;                       // 4096*8192 bf16 = 64 MB
  size_t off = (size_t)4096 * 8192 * 2;
  unsigned short* lnadj = (unsigned short*)(ws + off);  off += (size_t)2048 * 4096 * 2;
  unsigned short* lnfeats = (unsigned short*)(ws + off); off += (size_t)2048 * 1024 * 2;
  float* h45 = (float*)(ws + off);                      off += (size_t)2048 * 512 * 4;
  float* wT6 = (float*)(ws + off);                      off += (size_t)512 * 64 * 4;

  hipLaunchKernelGGL(ot_kernel, dim3(2048, 2), dim3(64), 0, stream,
                     x, w1, w2, fc2w, fc2b, fc3w, fc3b, bin_score, Pbuf);
  hipLaunchKernelGGL(transpose_kernel, dim3(32), dim3(256), 0, stream, fc6w, wT6, 64, 512);
  hipLaunchKernelGGL(align_kernel, dim3(2048), dim3(256), 0, stream,
                     Pbuf, adj, x, alpha, ln1g, ln1b, ln2g, ln2b, lnadj, lnfeats);
  hipLaunchKernelGGL(gemm_mfma_kernel, dim3(32, 4), dim3(256), 0, stream,
                     lnadj, fc4w, fc4b, h45, 4096, 512, 0);
  hipLaunchKernelGGL(gemm_mfma_kernel, dim3(32, 4), dim3(256), 0, stream,
                     lnfeats, fc5w, fc5b, h45, 1024, 512, 256);
  hipLaunchKernelGGL(head_kernel, dim3(256), dim3(256), 0, stream,
                     h45, wT6, fc6b, fc7w, fc7b, out);
}

// Round 7
// 240.207 us; speedup vs baseline: 3.4411x; 1.0093x over previous
//
#include <hip/hip_runtime.h>
#include <hip/hip_bf16.h>
#include <hip/hip_fp16.h>

// Problem constants
#define B_   2048
#define NN   128    // NMAX
#define MM   64     // HN
#define HD_  128
#define IND  18
#define FD_  16

typedef unsigned int u32;
typedef _Float16 h2_t __attribute__((ext_vector_type(2)));
typedef __attribute__((ext_vector_type(8))) short bf16x8;
typedef __attribute__((ext_vector_type(4))) float f32x4;

__device__ __forceinline__ float fdot2f(u32 a, u32 b, float c) {
#if defined(__has_builtin)
#if __has_builtin(__builtin_amdgcn_fdot2)
  return __builtin_amdgcn_fdot2(__builtin_bit_cast(h2_t, a),
                                __builtin_bit_cast(h2_t, b), c, false);
#else
  h2_t x = __builtin_bit_cast(h2_t, a), y = __builtin_bit_cast(h2_t, b);
  return c + (float)x[0] * (float)y[0] + (float)x[1] * (float)y[1];
#endif
#else
  h2_t x = __builtin_bit_cast(h2_t, a), y = __builtin_bit_cast(h2_t, b);
  return c + (float)x[0] * (float)y[0] + (float)x[1] * (float)y[1];
#endif
}

__device__ __forceinline__ u32 pk2(float a, float b) {
#if defined(__has_builtin)
#if __has_builtin(__builtin_amdgcn_cvt_pkrtz)
  return __builtin_bit_cast(u32, __builtin_amdgcn_cvt_pkrtz(a, b));
#else
  __half ha = __float2half_rn(a), hb = __float2half_rn(b);
  return (u32)__half_as_ushort(ha) | ((u32)__half_as_ushort(hb) << 16);
#endif
#else
  __half ha = __float2half_rn(a), hb = __float2half_rn(b);
  return (u32)__half_as_ushort(ha) | ((u32)__half_as_ushort(hb) << 16);
#endif
}

__device__ __forceinline__ float rcpf_(float x) {
#if defined(__has_builtin)
#if __has_builtin(__builtin_amdgcn_rcpf)
  return __builtin_amdgcn_rcpf(x);
#else
  return 1.0f / x;
#endif
#else
  return 1.0f / x;
#endif
}

__device__ __forceinline__ float h_lo(u32 d) {
  return __half2float(__ushort_as_half((unsigned short)(d & 0xffffu)));
}
__device__ __forceinline__ float h_hi(u32 d) {
  return __half2float(__ushort_as_half((unsigned short)(d >> 16)));
}

__device__ __forceinline__ float bf2f(unsigned short u) {
  union { float f; u32 i; } z; z.i = ((u32)u) << 16; return z.f;
}
__device__ __forceinline__ unsigned short f2bf(float f) {
  union { float fv; u32 u; } z; z.fv = f;
  u32 lsb = (z.u >> 16) & 1u;
  return (unsigned short)((z.u + 0x7fffu + lsb) >> 16);
}
__device__ __forceinline__ u32 bfpk(float a, float b) {
  return (u32)f2bf(a) | ((u32)f2bf(b) << 16);
}

// ---------------------------------------------------------------------------
// Kernel A: ONE WAVE per (batch, stream) OT problem. grid (2048,2), block 64.
// Phase 1 on bf16 MFMA (R6, verified). Sinkhorn: exp-space, register K.
// R7 change: TOL 3e-4 -> 1.5e-3 (above f16 u/v-exchange noise floor ~5e-4,
// so the __all exit actually fires; K ~= exp([0,0.4]) => kappa ~0.4 =>
// ~4-6 iterations to converge), convergence checked EVERY iteration.
// ---------------------------------------------------------------------------
__launch_bounds__(64, 2)
__global__ void ot_kernel(const float* __restrict__ x,
                          const float* __restrict__ w1,
                          const float* __restrict__ w2,
                          const float* __restrict__ fc2w, const float* __restrict__ fc2b,
                          const float* __restrict__ fc3w, const float* __restrict__ fc3b,
                          const float* __restrict__ bin_score,
                          unsigned short* __restrict__ Pbuf)
{
  __shared__ __align__(16) u32 Ksh[64 * 68];              // K f16, pitch 68 dw (136 h)
  __shared__ __align__(16) unsigned short actL[16 * 136]; // act slice bf16
  __shared__ __align__(16) u32 vhs[64];                   // v packed f16 pairs
  __shared__ __align__(16) u32 uhs[32];                   // u packed f16 pairs

  const int l = threadIdx.x;
  const int b = blockIdx.x, s = blockIdx.y;
  const int l15 = l & 15, q = l >> 4;
  const float* wm = s ? w2 : w1;
  const float* fw = s ? fc3w : fc2w;
  const float* fb = s ? fc3b : fc2b;
  unsigned short* Kshh = reinterpret_cast<unsigned short*>(Ksh);

  // ---- preload w A-frags (rows m = 16at+l15, ch-octet q within kt) ----
  uint4 wA[4][4];
  #pragma unroll
  for (int at = 0; at < 4; ++at) {
    const float* wrow = wm + (size_t)(16 * at + l15) * 128;
    #pragma unroll
    for (int kt = 0; kt < 4; ++kt) {
      float4 va = *reinterpret_cast<const float4*>(wrow + 32 * kt + 8 * q);
      float4 vb = *reinterpret_cast<const float4*>(wrow + 32 * kt + 8 * q + 4);
      wA[at][kt] = make_uint4(bfpk(va.x, va.y), bfpk(va.z, va.w),
                              bfpk(vb.x, vb.y), bfpk(vb.z, vb.w));
    }
  }
  // ---- preload fcw B-frags (col ch = 16nt+l15, ind-octet q, K=32 zero-pad) ----
  uint4 fcwB[8];
  #pragma unroll
  for (int nt = 0; nt < 8; ++nt) {
    const int ch = 16 * nt + l15;
    uint4 o = make_uint4(0u, 0u, 0u, 0u);
    if (s) {
      if (q < 2) {
        const float* fr = fw + (size_t)ch * 16 + 8 * q;
        float4 va = *reinterpret_cast<const float4*>(fr);
        float4 vb = *reinterpret_cast<const float4*>(fr + 4);
        o = make_uint4(bfpk(va.x, va.y), bfpk(va.z, va.w),
                       bfpk(vb.x, vb.y), bfpk(vb.z, vb.w));
      }
    } else {
      if (q == 0) o.x = bfpk(fw[ch * 2], fw[ch * 2 + 1]);
    }
    fcwB[nt] = o;
  }
  float bb[8];
  #pragma unroll
  for (int nt = 0; nt < 8; ++nt) bb[nt] = fb[16 * nt + l15];

  // ---- preload x A-frags (row node = 16mt+l15, ind-octet q) ----
  uint4 xa[8];
  #pragma unroll
  for (int mt = 0; mt < 8; ++mt) {
    const int node = 16 * mt + l15;
    const float* xp = x + ((size_t)b * NN + node) * IND + (s ? 2 : 0);
    uint4 o = make_uint4(0u, 0u, 0u, 0u);
    if (s) {
      if (q < 2) {
        float2 p0 = *reinterpret_cast<const float2*>(xp + 8 * q);
        float2 p1 = *reinterpret_cast<const float2*>(xp + 8 * q + 2);
        float2 p2 = *reinterpret_cast<const float2*>(xp + 8 * q + 4);
        float2 p3 = *reinterpret_cast<const float2*>(xp + 8 * q + 6);
        o = make_uint4(bfpk(p0.x, p0.y), bfpk(p1.x, p1.y),
                       bfpk(p2.x, p2.y), bfpk(p3.x, p3.y));
      }
    } else {
      if (q == 0) {
        float2 p0 = *reinterpret_cast<const float2*>(xp);
        o.x = bfpk(p0.x, p0.y);
      }
    }
    xa[mt] = o;
  }
  const float ebs = __expf(bin_score[0]);

  // ---- Phase 1: 8 slices of 16 nodes ----
  #pragma unroll
  for (int mt = 0; mt < 8; ++mt) {
    f32x4 acc[8];
    #pragma unroll
    for (int nt = 0; nt < 8; ++nt)
      acc[nt] = __builtin_amdgcn_mfma_f32_16x16x32_bf16(
          __builtin_bit_cast(bf16x8, xa[mt]), __builtin_bit_cast(bf16x8, fcwB[nt]),
          f32x4{0.f, 0.f, 0.f, 0.f}, 0, 0, 0);
    #pragma unroll
    for (int nt = 0; nt < 8; ++nt) {
      #pragma unroll
      for (int r = 0; r < 4; ++r) {
        float v = fmaxf(acc[nt][r] + bb[nt], 0.0f);
        actL[(4 * q + r) * 136 + 16 * nt + l15] = f2bf(v);
      }
    }
    uint4 sB[4];
    #pragma unroll
    for (int kt = 0; kt < 4; ++kt)
      sB[kt] = *reinterpret_cast<const uint4*>(&actL[l15 * 136 + 32 * kt + 8 * q]);
    #pragma unroll
    for (int at = 0; at < 4; ++at) {
      f32x4 sa = f32x4{0.f, 0.f, 0.f, 0.f};
      #pragma unroll
      for (int kt = 0; kt < 4; ++kt)
        sa = __builtin_amdgcn_mfma_f32_16x16x32_bf16(
            __builtin_bit_cast(bf16x8, wA[at][kt]), __builtin_bit_cast(bf16x8, sB[kt]),
            sa, 0, 0, 0);
      #pragma unroll
      for (int r = 0; r < 4; ++r) {
        float kv = fminf(__expf(fmaxf(sa[r], 0.0f)), 60000.0f);
        Kshh[(16 * at + 4 * q + r) * 136 + 16 * mt + l15] =
            __half_as_ushort(__float2half_rn(kv));
      }
    }
  }

  // ---- register K tiles ----
  u32 kr[64];
  #pragma unroll
  for (int t = 0; t < 16; ++t) {
    uint4 kv = *reinterpret_cast<const uint4*>(Ksh + l * 68 + 4 * t);
    kr[4 * t + 0] = kv.x; kr[4 * t + 1] = kv.y;
    kr[4 * t + 2] = kv.z; kr[4 * t + 3] = kv.w;
  }
  u32 kta[32], ktb[32];
  #pragma unroll
  for (int j = 0; j < 32; ++j) {
    u32 d0 = Ksh[(2 * j) * 68 + l];
    u32 d1 = Ksh[(2 * j + 1) * 68 + l];
    kta[j] = (d0 & 0xffffu) | (d1 << 16);
    ktb[j] = (d0 >> 16) | (d1 & 0xffff0000u);
  }

  // ---- Phase 2: barrier-free exp-space Sinkhorn ----
  vhs[l] = 0x3C003C00u;
  float v128 = 1.0f, sum_v = 129.0f;
  float u_old = 0.0f, vo0 = 1.0f, vo1 = 1.0f;
  float ur = 0.0f;
  const float TOL = 1.5e-3f;

  for (int it = 0; it < 100; ++it) {
    const float u64v = 128.0f * rcpf_(ebs * sum_v);
    float a0 = ebs * v128, a1 = 0.f, a2 = 0.f, a3 = 0.f;
    const uint4* vh4 = reinterpret_cast<const uint4*>(vhs);
    #pragma unroll
    for (int t = 0; t < 16; ++t) {
      uint4 vv = vh4[t];
      a0 = fdot2f(kr[4 * t + 0], vv.x, a0);
      a1 = fdot2f(kr[4 * t + 1], vv.y, a1);
      a2 = fdot2f(kr[4 * t + 2], vv.z, a2);
      a3 = fdot2f(kr[4 * t + 3], vv.w, a3);
    }
    float urn = rcpf_((a0 + a1) + (a2 + a3));
    float m1 = fabsf(urn - u_old) - TOL * urn;
    u_old = urn; ur = urn;
    float su = urn;
    su += __shfl_xor(su, 1);  su += __shfl_xor(su, 2);
    su += __shfl_xor(su, 4);  su += __shfl_xor(su, 8);
    su += __shfl_xor(su, 16); su += __shfl_xor(su, 32);
    const float sum_u = su + u64v;
    const float v128n = 64.0f * rcpf_(ebs * sum_u);
    float upr = __shfl_xor(urn, 1);
    if (!(l & 1)) uhs[l >> 1] = pk2(urn, upr);
    float c0a = ebs * u64v, c0b = 0.f, c1a = ebs * u64v, c1b = 0.f;
    const uint4* uh4 = reinterpret_cast<const uint4*>(uhs);
    #pragma unroll
    for (int t = 0; t < 8; ++t) {
      uint4 uu = uh4[t];
      c0a = fdot2f(kta[4 * t + 0], uu.x, c0a);
      c0b = fdot2f(kta[4 * t + 1], uu.y, c0b);
      c0a = fdot2f(kta[4 * t + 2], uu.z, c0a);
      c0b = fdot2f(kta[4 * t + 3], uu.w, c0b);
      c1a = fdot2f(ktb[4 * t + 0], uu.x, c1a);
      c1b = fdot2f(ktb[4 * t + 1], uu.y, c1b);
      c1a = fdot2f(ktb[4 * t + 2], uu.z, c1a);
      c1b = fdot2f(ktb[4 * t + 3], uu.w, c1b);
    }
    float v0n = rcpf_(c0a + c0b);
    float v1n = rcpf_(c1a + c1b);
    float m2 = fabsf(v0n - vo0) - TOL * v0n;
    float m3 = fabsf(v1n - vo1) - TOL * v1n;
    vo0 = v0n; vo1 = v1n;
    vhs[l] = pk2(v0n, v1n);
    float sv = v0n + v1n;
    sv += __shfl_xor(sv, 1);  sv += __shfl_xor(sv, 2);
    sv += __shfl_xor(sv, 4);  sv += __shfl_xor(sv, 8);
    sv += __shfl_xor(sv, 16); sv += __shfl_xor(sv, 32);
    sum_v = sv + v128n;
    v128 = v128n;
    float mcond = fmaxf(m1, fmaxf(m2, m3));
    if (__all(mcond <= 0.0f)) break;
  }

  // ---- Phase 3: P[l][n] = K*u*v -> bf16 ----
  {
    unsigned short* Pout = Pbuf + ((size_t)(s * B_ + b)) * (MM * NN);
    uint4* P4 = reinterpret_cast<uint4*>(Pout);
    const uint4* vh4 = reinterpret_cast<const uint4*>(vhs);
    #pragma unroll
    for (int t = 0; t < 16; ++t) {
      uint4 vv = vh4[t];
      u32 o0, o1, o2, o3;
#define PDW(KD, VD, OUT) do {                                                 \
      float p0 = h_lo(KD) * ur * h_lo(VD);                                    \
      float p1 = h_hi(KD) * ur * h_hi(VD);                                    \
      OUT = (u32)f2bf(p0) | ((u32)f2bf(p1) << 16);                            \
    } while (0)
      PDW(kr[4 * t + 0], vv.x, o0);
      PDW(kr[4 * t + 1], vv.y, o1);
      PDW(kr[4 * t + 2], vv.z, o2);
      PDW(kr[4 * t + 3], vv.w, o3);
#undef PDW
      P4[l * 16 + t] = make_uint4(o0, o1, o2, o3);
    }
  }
}

// ---------------------------------------------------------------------------
// Kernel B (MFMA): unchanged (passed).
// ---------------------------------------------------------------------------
#define AP 136   // bf16 row pitch (272 B, 16B aligned)

__device__ __forceinline__ bf16x8 ldfrag(const unsigned short* p) {
  return __builtin_bit_cast(bf16x8, *reinterpret_cast<const uint4*>(p));
}
__device__ __forceinline__ u32 comb2(u32 ps, u32 pf, float a, float na) {
  float r0 = a * bf2f((unsigned short)(ps & 0xffffu)) + na * bf2f((unsigned short)(pf & 0xffffu));
  float r1 = a * bf2f((unsigned short)(ps >> 16)) + na * bf2f((unsigned short)(pf >> 16));
  return (u32)f2bf(r0) | ((u32)f2bf(r1) << 16);
}

__launch_bounds__(256, 2)
__global__ void align_kernel(const unsigned short* __restrict__ Pbuf,
                             const float* __restrict__ adj,
                             const float* __restrict__ x,
                             const float* __restrict__ alpha_p,
                             const float* __restrict__ ln1g, const float* __restrict__ ln1b,
                             const float* __restrict__ ln2g, const float* __restrict__ ln2b,
                             unsigned short* __restrict__ lnadj,
                             unsigned short* __restrict__ lnfeats)
{
  __shared__ __align__(16) unsigned short adjb[128 * AP];
  __shared__ __align__(16) unsigned short Pms[64 * AP];
  __shared__ __align__(16) unsigned short Z1T[64 * AP];
  __shared__ __align__(16) unsigned short xfT[16 * AP];
  __shared__ float red[16];

  const int tid = threadIdx.x;
  const int b = blockIdx.x;
  const int w = tid >> 6;
  const int lane = tid & 63;
  const int l15 = lane & 15;
  const int q = lane >> 4;
  const float a = 1.0f / (1.0f + __expf(-alpha_p[0]));
  const float na = 1.0f - a;

  {
    const float4* src = reinterpret_cast<const float4*>(adj + (size_t)b * (NN * NN));
    for (int i = tid; i < 128 * 32; i += 256) {
      int row = i >> 5, c4 = i & 31;
      float4 v = src[i];
      u32 w0 = (u32)f2bf(v.x) | ((u32)f2bf(v.y) << 16);
      u32 w1 = (u32)f2bf(v.z) | ((u32)f2bf(v.w) << 16);
      *reinterpret_cast<uint2*>(&adjb[row * AP + c4 * 4]) = make_uint2(w0, w1);
    }
  }
  {
    const uint4* Ps4 = reinterpret_cast<const uint4*>(Pbuf + (size_t)b * (MM * NN));
    const uint4* Pf4 = reinterpret_cast<const uint4*>(Pbuf + ((size_t)B_ + b) * (MM * NN));
    for (int i = tid; i < 64 * 16; i += 256) {
      int row = i >> 4, g = i & 15;
      uint4 sa = Ps4[i];
      uint4 fa = Pf4[i];
      uint4 o;
      o.x = comb2(sa.x, fa.x, a, na); o.y = comb2(sa.y, fa.y, a, na);
      o.z = comb2(sa.z, fa.z, a, na); o.w = comb2(sa.w, fa.w, a, na);
      *reinterpret_cast<uint4*>(&Pms[row * AP + g * 8]) = o;
    }
  }
  for (int i = tid; i < 2048; i += 256) {
    int n = i & 127, f = i >> 7;
    xfT[f * AP + n] = f2bf(x[((size_t)b * NN + n) * IND + 2 + f]);
  }
  __syncthreads();

  {
    f32x4 acc[2][4];
    #pragma unroll
    for (int i = 0; i < 2; ++i)
      #pragma unroll
      for (int j = 0; j < 4; ++j) acc[i][j] = f32x4{0.f, 0.f, 0.f, 0.f};
    #pragma unroll
    for (int kt = 0; kt < 4; ++kt) {
      const int d0 = 32 * kt + 8 * q;
      bf16x8 bf[4];
      #pragma unroll
      for (int j = 0; j < 4; ++j)
        bf[j] = ldfrag(&Pms[(16 * j + l15) * AP + d0]);
      #pragma unroll
      for (int ai = 0; ai < 2; ++ai) {
        bf16x8 af = ldfrag(&adjb[(32 * w + 16 * ai + l15) * AP + d0]);
        #pragma unroll
        for (int j = 0; j < 4; ++j)
          acc[ai][j] = __builtin_amdgcn_mfma_f32_16x16x32_bf16(af, bf[j], acc[ai][j], 0, 0, 0);
      }
    }
    #pragma unroll
    for (int ai = 0; ai < 2; ++ai) {
      #pragma unroll
      for (int j = 0; j < 4; ++j) {
        const int k = 16 * j + l15;
        const int nbase = 32 * w + 16 * ai + 4 * q;
        u32 w0 = (u32)f2bf(acc[ai][j][0]) | ((u32)f2bf(acc[ai][j][1]) << 16);
        u32 w1 = (u32)f2bf(acc[ai][j][2]) | ((u32)f2bf(acc[ai][j][3]) << 16);
        *reinterpret_cast<uint2*>(&Z1T[k * AP + nbase]) = make_uint2(w0, w1);
      }
    }
  }
  __syncthreads();

  f32x4 acc2[4];
  f32x4 acc3 = f32x4{0.f, 0.f, 0.f, 0.f};
  #pragma unroll
  for (int j = 0; j < 4; ++j) acc2[j] = f32x4{0.f, 0.f, 0.f, 0.f};
  #pragma unroll
  for (int nt = 0; nt < 4; ++nt) {
    const int n0 = 32 * nt + 8 * q;
    bf16x8 af = ldfrag(&Pms[(16 * w + l15) * AP + n0]);
    #pragma unroll
    for (int j = 0; j < 4; ++j) {
      bf16x8 bv = ldfrag(&Z1T[(16 * j + l15) * AP + n0]);
      acc2[j] = __builtin_amdgcn_mfma_f32_16x16x32_bf16(af, bv, acc2[j], 0, 0, 0);
    }
    bf16x8 bx = ldfrag(&xfT[l15 * AP + n0]);
    acc3 = __builtin_amdgcn_mfma_f32_16x16x32_bf16(af, bx, acc3, 0, 0, 0);
  }

  {
    float s1 = 0.f, q1 = 0.f, s2 = 0.f, q2 = 0.f;
    #pragma unroll
    for (int j = 0; j < 4; ++j)
      #pragma unroll
      for (int r = 0; r < 4; ++r) { float v = acc2[j][r]; s1 += v; q1 += v * v; }
    #pragma unroll
    for (int r = 0; r < 4; ++r) { float v = acc3[r]; s2 += v; q2 += v * v; }
    #pragma unroll
    for (int off = 1; off < 64; off <<= 1) {
      s1 += __shfl_xor(s1, off); q1 += __shfl_xor(q1, off);
      s2 += __shfl_xor(s2, off); q2 += __shfl_xor(q2, off);
    }
    if (lane == 0) { red[w] = s1; red[4 + w] = q1; red[8 + w] = s2; red[12 + w] = q2; }
  }
  __syncthreads();
  const float S1 = red[0] + red[1] + red[2] + red[3];
  const float Q1 = red[4] + red[5] + red[6] + red[7];
  const float S2 = red[8] + red[9] + red[10] + red[11];
  const float Q2 = red[12] + red[13] + red[14] + red[15];
  const float mean1 = S1 * (1.0f / 4096.0f);
  const float rstd1 = rsqrtf(Q1 * (1.0f / 4096.0f) - mean1 * mean1 + 1e-5f);
  const float mean2 = S2 * (1.0f / 1024.0f);
  const float rstd2 = rsqrtf(Q2 * (1.0f / 1024.0f) - mean2 * mean2 + 1e-5f);

  unsigned short* ob1 = adjb;
  unsigned short* ob2 = Z1T;
  #pragma unroll
  for (int j = 0; j < 4; ++j) {
    const int k = 16 * j + l15;
    #pragma unroll
    for (int r = 0; r < 4; ++r) {
      const int m = 16 * w + 4 * q + r;
      const int pos = m * 64 + k;
      float vv = (acc2[j][r] - mean1) * rstd1 * ln1g[pos] + ln1b[pos];
      ob1[pos] = f2bf(vv);
    }
  }
  {
    const int f = l15;
    #pragma unroll
    for (int r = 0; r < 4; ++r) {
      const int m = 16 * w + 4 * q + r;
      const int pos = m * 16 + f;
      float vv = (acc3[r] - mean2) * rstd2 * ln2g[pos] + ln2b[pos];
      ob2[pos] = f2bf(vv);
    }
  }
  __syncthreads();
  {
    const uint4* sp = reinterpret_cast<const uint4*>(ob1);
    uint4* dp = reinterpret_cast<uint4*>(lnadj + (size_t)b * 4096);
    for (int i = tid; i < 512; i += 256) dp[i] = sp[i];
    if (tid < 128)
      reinterpret_cast<uint4*>(lnfeats + (size_t)b * 1024)[tid] =
          reinterpret_cast<const uint4*>(ob2)[tid];
  }
}

// ---------------------------------------------------------------------------
// Kernel C (MFMA): unchanged.
// ---------------------------------------------------------------------------
#define GP 72
__launch_bounds__(256, 2)
__global__ void gemm_mfma_kernel(const unsigned short* __restrict__ A,
                                 const float* __restrict__ W,
                                 const float* __restrict__ bias,
                                 float* __restrict__ C,
                                 int K, int ldc, int coff)
{
  __shared__ __align__(16) unsigned short At[64 * GP];
  __shared__ __align__(16) unsigned short Wt[64 * GP];
  const int tid = threadIdx.x;
  const int m0 = blockIdx.x * 64;
  const int n0 = blockIdx.y * 64;
  const int w = tid >> 6, lane = tid & 63;
  const int l15 = lane & 15, q = lane >> 4;
  const int srow = tid >> 2, sko = (tid & 3) * 16;

  f32x4 acc[4];
  #pragma unroll
  for (int j = 0; j < 4; ++j) acc[j] = f32x4{0.f, 0.f, 0.f, 0.f};

  for (int kc = 0; kc < K; kc += 64) {
    __syncthreads();
    {
      const unsigned short* ap = &A[(size_t)(m0 + srow) * K + kc + sko];
      *reinterpret_cast<uint4*>(&At[srow * GP + sko]) =
          *reinterpret_cast<const uint4*>(ap);
      *reinterpret_cast<uint4*>(&At[srow * GP + sko + 8]) =
          *reinterpret_cast<const uint4*>(ap + 8);
      const float* wp = &W[(size_t)(n0 + srow) * K + kc + sko];
      const float4 v0 = reinterpret_cast<const float4*>(wp)[0];
      const float4 v1 = reinterpret_cast<const float4*>(wp)[1];
      const float4 v2 = reinterpret_cast<const float4*>(wp)[2];
      const float4 v3 = reinterpret_cast<const float4*>(wp)[3];
      uint4 o0, o1;
      o0.x = (u32)f2bf(v0.x) | ((u32)f2bf(v0.y) << 16);
      o0.y = (u32)f2bf(v0.z) | ((u32)f2bf(v0.w) << 16);
      o0.z = (u32)f2bf(v1.x) | ((u32)f2bf(v1.y) << 16);
      o0.w = (u32)f2bf(v1.z) | ((u32)f2bf(v1.w) << 16);
      o1.x = (u32)f2bf(v2.x) | ((u32)f2bf(v2.y) << 16);
      o1.y = (u32)f2bf(v2.z) | ((u32)f2bf(v2.w) << 16);
      o1.z = (u32)f2bf(v3.x) | ((u32)f2bf(v3.y) << 16);
      o1.w = (u32)f2bf(v3.z) | ((u32)f2bf(v3.w) << 16);
      *reinterpret_cast<uint4*>(&Wt[srow * GP + sko]) = o0;
      *reinterpret_cast<uint4*>(&Wt[srow * GP + sko + 8]) = o1;
    }
    __syncthreads();
    #pragma unroll
    for (int s = 0; s < 2; ++s) {
      bf16x8 af = ldfrag(&At[(16 * w + l15) * GP + 32 * s + 8 * q]);
      #pragma unroll
      for (int j = 0; j < 4; ++j) {
        bf16x8 bf = ldfrag(&Wt[(16 * j + l15) * GP + 32 * s + 8 * q]);
        acc[j] = __builtin_amdgcn_mfma_f32_16x16x32_bf16(af, bf, acc[j], 0, 0, 0);
      }
    }
  }
  #pragma unroll
  for (int j = 0; j < 4; ++j) {
    const int col = n0 + 16 * j + l15;
    const float bb = bias[col];
    #pragma unroll
    for (int r = 0; r < 4; ++r) {
      const int m = m0 + 16 * w + 4 * q + r;
      C[(size_t)m * ldc + coff + col] = fmaxf(acc[j][r] + bb, 0.0f);
    }
  }
}

// ---------------------------------------------------------------------------
// Kernel D: unchanged (8 rows/block).
// ---------------------------------------------------------------------------
__launch_bounds__(256)
__global__ void head_kernel(const float* __restrict__ h45,
                            const float* __restrict__ wT6,   // [512][64]
                            const float* __restrict__ b6,
                            const float* __restrict__ w7,    // [10][64]
                            const float* __restrict__ b7,
                            float* __restrict__ out)
{
  __shared__ float row[8][512];
  __shared__ float h6[8][64];
  __shared__ float zb[8][12];
  const int tid = threadIdx.x;
  const int r0 = blockIdx.x * 8;
  for (int i = tid; i < 8 * 128; i += 256) {
    int r = i >> 7, c4 = i & 127;
    *reinterpret_cast<float4*>(&row[r][c4 * 4]) =
        reinterpret_cast<const float4*>(h45 + (size_t)(r0 + r) * 512)[c4];
  }
  __syncthreads();
  const int o = tid & 63, rg = tid >> 6;
  float a0 = b6[o], a1 = a0;
  #pragma unroll 8
  for (int k = 0; k < 512; ++k) {
    float wv = wT6[k * 64 + o];
    a0 += row[rg][k] * wv;
    a1 += row[rg + 4][k] * wv;
  }
  h6[rg][o] = fmaxf(a0, 0.0f);
  h6[rg + 4][o] = fmaxf(a1, 0.0f);
  __syncthreads();
  if (tid < 80) {
    int r = tid / 10, c = tid - r * 10;
    float z = b7[c];
    #pragma unroll
    for (int k = 0; k < 64; ++k) z += h6[r][k] * w7[c * 64 + k];
    zb[r][c] = z;
  }
  __syncthreads();
  if (tid < 80) {
    int r = tid / 10, c = tid - r * 10;
    float mx = zb[r][0];
    #pragma unroll
    for (int j = 1; j < 10; ++j) mx = fmaxf(mx, zb[r][j]);
    float se = 0.f;
    #pragma unroll
    for (int j = 0; j < 10; ++j) se += __expf(zb[r][j] - mx);
    out[(size_t)(r0 + r) * 10 + c] = zb[r][c] - mx - __logf(se);
  }
}

__global__ void transpose_kernel(const float* __restrict__ in, float* __restrict__ outp,
                                 int R, int Cc)
{
  int idx = blockIdx.x * blockDim.x + threadIdx.x;
  int total = R * Cc;
  for (; idx < total; idx += gridDim.x * blockDim.x) {
    int rr = idx / Cc, cc = idx - rr * Cc;
    outp[cc * R + rr] = in[idx];
  }
}

// ---------------------------------------------------------------------------
extern "C" void kernel_launch(void* const* d_in, const int* in_sizes, int n_in,
                              void* d_out, int out_size, void* d_ws, size_t ws_size,
                              hipStream_t stream)
{
  (void)in_sizes; (void)n_in; (void)out_size; (void)ws_size;
  const float* x    = (const float*)d_in[0];
  const float* adj  = (const float*)d_in[1];
  const float* w1   = (const float*)d_in[2];
  const float* w2   = (const float*)d_in[3];
  const float* alpha = (const float*)d_in[4];
  const float* bin_score = (const float*)d_in[5];
  const float* fc2w = (const float*)d_in[6];
  const float* fc2b = (const float*)d_in[7];
  const float* fc3w = (const float*)d_in[8];
  const float* fc3b = (const float*)d_in[9];
  const float* ln1g = (const float*)d_in[10];
  const float* ln1b = (const float*)d_in[11];
  const float* fc4w = (const float*)d_in[12];
  const float* fc4b = (const float*)d_in[13];
  const float* ln2g = (const float*)d_in[14];
  const float* ln2b = (const float*)d_in[15];
  const float* fc5w = (const float*)d_in[16];
  const float* fc5b = (const float*)d_in[17];
  const float* fc6w = (const float*)d_in[18];
  const float* fc6b = (const float*)d_in[19];
  const float* fc7w = (const float*)d_in[20];
  const float* fc7b = (const float*)d_in[21];
  float* out = (float*)d_out;

  char* ws = (char*)d_ws;
  unsigned short* Pbuf = (unsigned short*)ws;                       // 4096*8192 bf16 = 64 MB
  size_t off = (size_t)4096 * 8192 * 2;
  unsigned short* lnadj = (unsigned short*)(ws + off);  off += (size_t)2048 * 4096 * 2;
  unsigned short* lnfeats = (unsigned short*)(ws + off); off += (size_t)2048 * 1024 * 2;
  float* h45 = (float*)(ws + off);                      off += (size_t)2048 * 512 * 4;
  float* wT6 = (float*)(ws + off);                      off += (size_t)512 * 64 * 4;

  hipLaunchKernelGGL(ot_kernel, dim3(2048, 2), dim3(64), 0, stream,
                     x, w1, w2, fc2w, fc2b, fc3w, fc3b, bin_score, Pbuf);
  hipLaunchKernelGGL(transpose_kernel, dim3(32), dim3(256), 0, stream, fc6w, wT6, 64, 512);
  hipLaunchKernelGGL(align_kernel, dim3(2048), dim3(256), 0, stream,
                     Pbuf, adj, x, alpha, ln1g, ln1b, ln2g, ln2b, lnadj, lnfeats);
  hipLaunchKernelGGL(gemm_mfma_kernel, dim3(32, 4), dim3(256), 0, stream,
                     lnadj, fc4w, fc4b, h45, 4096, 512, 0);
  hipLaunchKernelGGL(gemm_mfma_kernel, dim3(32, 4), dim3(256), 0, stream,
                     lnfeats, fc5w, fc5b, h45, 1024, 512, 256);
  hipLaunchKernelGGL(head_kernel, dim3(256), dim3(256), 0, stream,
                     h45, wT6, fc6b, fc7w, fc7b, out);
}